// Round 3
// baseline (5269.627 us; speedup 1.0000x reference)
//
#include <hip/hip_runtime.h>
#include <hip/hip_bf16.h>
#include <math.h>

using bf16 = __hip_bfloat16;
typedef short bf16x8 __attribute__((ext_vector_type(8)));
typedef float f32x4 __attribute__((ext_vector_type(4)));

static constexpr int B = 2, S = 2048, D = 1024, H = 16, HD = 64, DFF = 4096;
static constexpr int NR = B * S; // 4096 rows
static constexpr float EPS = 1e-5f;

__device__ __forceinline__ float b2f(bf16 v) { return __bfloat162float(v); }
__device__ __forceinline__ bf16 f2b(float v) { return __float2bfloat16(v); }

// ---------------- fp32 -> bf16 converter (8 elems/thread) ----------------
__global__ __launch_bounds__(256) void conv_kernel(const float* __restrict__ src,
                                                   bf16* __restrict__ dst, int n8) {
    int i = blockIdx.x * 256 + threadIdx.x;
    const int stride = gridDim.x * 256;
    for (; i < n8; i += stride) {
        float4 a = ((const float4*)src)[2 * i];
        float4 b = ((const float4*)src)[2 * i + 1];
        union { ushort4 u4[2]; bf16 h[8]; int4 v; } o;
        o.h[0] = f2b(a.x); o.h[1] = f2b(a.y); o.h[2] = f2b(a.z); o.h[3] = f2b(a.w);
        o.h[4] = f2b(b.x); o.h[5] = f2b(b.y); o.h[6] = f2b(b.z); o.h[7] = f2b(b.w);
        ((int4*)dst)[i] = o.v;
    }
}

// ---------------- LayerNorm: fp32 in, bf16 out; one block per row ----------------
__global__ __launch_bounds__(256) void ln_kernel(const float* __restrict__ x,
                                                 const float* __restrict__ g,
                                                 const float* __restrict__ b,
                                                 bf16* __restrict__ out) {
    const int row = blockIdx.x;
    const int tid = threadIdx.x;
    const float4 v4 = ((const float4*)(x + (size_t)row * D))[tid];
    float v[4] = {v4.x, v4.y, v4.z, v4.w};
    float s = v[0] + v[1] + v[2] + v[3];
    float sq = v[0] * v[0] + v[1] * v[1] + v[2] * v[2] + v[3] * v[3];
#pragma unroll
    for (int off = 32; off >= 1; off >>= 1) {
        s += __shfl_xor(s, off);
        sq += __shfl_xor(sq, off);
    }
    __shared__ float ssum[4], ssq[4];
    const int wave = tid >> 6;
    if ((tid & 63) == 0) { ssum[wave] = s; ssq[wave] = sq; }
    __syncthreads();
    s = ssum[0] + ssum[1] + ssum[2] + ssum[3];
    sq = ssq[0] + ssq[1] + ssq[2] + ssq[3];
    const float mu = s * (1.0f / D);
    const float var = sq * (1.0f / D) - mu * mu;
    const float rstd = rsqrtf(var + EPS);
    bf16* orow = out + (size_t)row * D;
#pragma unroll
    for (int i = 0; i < 4; ++i) {
        const int c = tid * 4 + i;
        orow[c] = f2b((v[i] - mu) * rstd * g[c] + b[c]);
    }
}

// ---------------- GEMM: C[M,N] = A[M,K] @ W[K,N] (+epilogue) ----------------
// 128x128 block tile, 4 waves 2x2, each wave 4x4 tiles of 16x16x32 bf16 MFMA.
// EPI 0: plain, bf16 out.  EPI 1: + fp32 bias + fp32 residual, fp32 out
// (res==C in-place OK: same-thread read-then-write).  EPI 2: + fp32 bias +
// exact GELU, bf16 out.
template <int EPI>
__global__ __launch_bounds__(256) void gemm_kernel(const bf16* __restrict__ A,
                                                   const bf16* __restrict__ W,
                                                   const float* __restrict__ bias,
                                                   const float* __restrict__ res,
                                                   void* __restrict__ Cv,
                                                   int M, int N, int K) {
    __shared__ __align__(16) bf16 As[128][40];   // [m][k], +8 pad
    __shared__ __align__(16) bf16 BsT[128][40];  // [n][k], +8 pad
    const int tm = blockIdx.x, tn = blockIdx.y;
    const int tid = threadIdx.x;
    const int wave = tid >> 6, lane = tid & 63;
    const int wm = wave >> 1, wn = wave & 1;
    const int quad = lane >> 4, l16 = lane & 15;

    f32x4 acc[4][4];
#pragma unroll
    for (int i = 0; i < 4; ++i)
#pragma unroll
        for (int j = 0; j < 4; ++j) acc[i][j] = (f32x4){0.f, 0.f, 0.f, 0.f};

    const int a_row = tid >> 1;        // 0..127
    const int a_c0 = (tid & 1) * 16;   // 0 or 16
    const int b_k = tid >> 3;          // 0..31
    const int b_n0 = (tid & 7) * 16;   // 0,16,..,112

    const bf16* Aptr = A + (size_t)(tm * 128 + a_row) * K + a_c0;
    const bf16* Wptr = W + (size_t)b_k * N + tn * 128 + b_n0;

    const int nk = K / 32;
    for (int kt = 0; kt < nk; ++kt) {
        __syncthreads();
        union { int4 i; bf16 h[8]; } ua0, ua1, ub0, ub1;
        ua0.i = *(const int4*)(Aptr);
        ua1.i = *(const int4*)(Aptr + 8);
        ub0.i = *(const int4*)(Wptr);
        ub1.i = *(const int4*)(Wptr + 8);
        *(int4*)&As[a_row][a_c0] = ua0.i;
        *(int4*)&As[a_row][a_c0 + 8] = ua1.i;
#pragma unroll
        for (int i = 0; i < 8; ++i) BsT[b_n0 + i][b_k] = ub0.h[i];
#pragma unroll
        for (int i = 0; i < 8; ++i) BsT[b_n0 + 8 + i][b_k] = ub1.h[i];
        __syncthreads();

        bf16x8 aF[4], bF[4];
#pragma unroll
        for (int mt = 0; mt < 4; ++mt)
            aF[mt] = *(const bf16x8*)&As[wm * 64 + mt * 16 + l16][quad * 8];
#pragma unroll
        for (int nt = 0; nt < 4; ++nt)
            bF[nt] = *(const bf16x8*)&BsT[wn * 64 + nt * 16 + l16][quad * 8];
#pragma unroll
        for (int mt = 0; mt < 4; ++mt)
#pragma unroll
            for (int nt = 0; nt < 4; ++nt)
                acc[mt][nt] = __builtin_amdgcn_mfma_f32_16x16x32_bf16(
                    aF[mt], bF[nt], acc[mt][nt], 0, 0, 0);

        Aptr += 32;
        Wptr += (size_t)32 * N;
    }

    // epilogue: C/D layout col = lane&15, row = quad*4 + j  [m89/m91-verified]
#pragma unroll
    for (int nt = 0; nt < 4; ++nt) {
        const int col = tn * 128 + wn * 64 + nt * 16 + l16;
        float bv = 0.f;
        if (EPI != 0) bv = bias[col];
#pragma unroll
        for (int mt = 0; mt < 4; ++mt) {
            const int row0 = tm * 128 + wm * 64 + mt * 16 + quad * 4;
#pragma unroll
            for (int j = 0; j < 4; ++j) {
                float v = acc[mt][nt][j];
                const size_t idx = (size_t)(row0 + j) * N + col;
                if (EPI == 1) {
                    v += bv + res[idx];
                    ((float*)Cv)[idx] = v;
                } else if (EPI == 2) {
                    v += bv;
                    v = 0.5f * v * (1.0f + erff(v * 0.70710678118654752f));
                    ((bf16*)Cv)[idx] = f2b(v);
                } else {
                    ((bf16*)Cv)[idx] = f2b(v);
                }
            }
        }
    }
}

// ---------------- Causal attention: one wave per query row ----------------
// Q/K/V layout: [B,S,H*HD] row-major; lane = head dim d.
__global__ __launch_bounds__(256) void attn_kernel(const bf16* __restrict__ Q,
                                                   const bf16* __restrict__ Kb,
                                                   const bf16* __restrict__ Vb,
                                                   bf16* __restrict__ ctx) {
    const int wid = blockIdx.x * 4 + (threadIdx.x >> 6);
    const int lane = threadIdx.x & 63;
    const int b = wid / (H * S);
    const int rem = wid % (H * S);
    const int h = rem / S;
    const int qi = rem % S;
    const size_t headoff = (size_t)b * S * D + (size_t)h * HD;
    const float qv = b2f(Q[headoff + (size_t)qi * D + lane]) * 0.125f; // 1/sqrt(64)
    float m = -3.0e38f, l = 0.f, acc = 0.f;
    const bf16* kp = Kb + headoff;
    const bf16* vp = Vb + headoff;
    for (int k = 0; k <= qi; ++k) {
        float p = qv * b2f(kp[(size_t)k * D + lane]);
#pragma unroll
        for (int off = 32; off >= 1; off >>= 1) p += __shfl_xor(p, off);
        const float mn = fmaxf(m, p);
        const float al = __expf(m - mn);
        const float pe = __expf(p - mn);
        l = l * al + pe;
        acc = acc * al + pe * b2f(vp[(size_t)k * D + lane]);
        m = mn;
    }
    ctx[headoff + (size_t)qi * D + lane] = f2b(acc / l);
}

// ---------------- launcher ----------------
extern "C" void kernel_launch(void* const* d_in, const int* in_sizes, int n_in,
                              void* d_out, int out_size, void* d_ws, size_t ws_size,
                              hipStream_t stream) {
    const float* x     = (const float*)d_in[0];
    const float* ln1_g = (const float*)d_in[1];
    const float* ln1_b = (const float*)d_in[2];
    const float* Wq    = (const float*)d_in[3];
    const float* Wk    = (const float*)d_in[4];
    const float* Wv    = (const float*)d_in[5];
    const float* Wo    = (const float*)d_in[6];
    const float* bo    = (const float*)d_in[7];
    const float* ln2_g = (const float*)d_in[8];
    const float* ln2_b = (const float*)d_in[9];
    const float* W1    = (const float*)d_in[10];
    const float* b1    = (const float*)d_in[11];
    const float* W2    = (const float*)d_in[12];
    const float* b2    = (const float*)d_in[13];
    float* out = (float*)d_out;

    // workspace layout (MB), lifetime-overlapped; peak 56 MB:
    //   [ 0, 8): h (LN1 out, bf16) -> ctx (attn out) -> W1c (bf16)
    //   [ 8,16): Qb (bf16)         -> h2 (LN2 out, bf16)
    //   [16,24): Kb (bf16)  \
    //   [24,32): Vb (bf16)   }     -> hff [16,48) (bf16, 32 MB)
    //   [32,48): (hff tail)
    //   [48,56): Wqc/Wkc/Wvc/Woc (2 MB each) -> W2c (bf16, 8 MB)
    //   x2 (fp32 residual stream, 16 MB) lives in d_out; final GEMM reads it
    //   in-place (same-thread read-then-write).
    char* ws = (char*)d_ws;
    const size_t MB = (size_t)1 << 20;
    bf16* h   = (bf16*)(ws + 0 * MB);
    bf16* ctx = (bf16*)(ws + 0 * MB);
    bf16* W1c = (bf16*)(ws + 0 * MB);
    bf16* Qb  = (bf16*)(ws + 8 * MB);
    bf16* h2  = (bf16*)(ws + 8 * MB);
    bf16* Kb  = (bf16*)(ws + 16 * MB);
    bf16* Vb  = (bf16*)(ws + 24 * MB);
    bf16* hff = (bf16*)(ws + 16 * MB);
    bf16* Wqc = (bf16*)(ws + 48 * MB);
    bf16* Wkc = (bf16*)(ws + 50 * MB);
    bf16* Wvc = (bf16*)(ws + 52 * MB);
    bf16* Woc = (bf16*)(ws + 54 * MB);
    bf16* W2c = (bf16*)(ws + 48 * MB);
    float* x2 = out;

    // --- 0) convert attention weights to bf16 ---
    conv_kernel<<<512, 256, 0, stream>>>(Wq, Wqc, D * D / 8);
    conv_kernel<<<512, 256, 0, stream>>>(Wk, Wkc, D * D / 8);
    conv_kernel<<<512, 256, 0, stream>>>(Wv, Wvc, D * D / 8);
    conv_kernel<<<512, 256, 0, stream>>>(Wo, Woc, D * D / 8);
    // --- 1) LN1: h = LN(x) ---
    ln_kernel<<<NR, 256, 0, stream>>>(x, ln1_g, ln1_b, h);
    // --- 2) Q,K,V = h @ W{q,k,v}   [4096,1024]x[1024,1024] ---
    dim3 g1(NR / 128, D / 128);
    gemm_kernel<0><<<g1, 256, 0, stream>>>(h, Wqc, nullptr, nullptr, Qb, NR, D, D);
    gemm_kernel<0><<<g1, 256, 0, stream>>>(h, Wkc, nullptr, nullptr, Kb, NR, D, D);
    gemm_kernel<0><<<g1, 256, 0, stream>>>(h, Wvc, nullptr, nullptr, Vb, NR, D, D);
    // --- 3) causal attention -> ctx (over dead h) ---
    attn_kernel<<<B * H * S / 4, 256, 0, stream>>>(Qb, Kb, Vb, ctx);
    // --- 4) x2 = x + ctx @ Wo + bo  (fp32, into d_out) ---
    gemm_kernel<1><<<g1, 256, 0, stream>>>(ctx, Woc, bo, x, x2, NR, D, D);
    // --- convert MLP weights into now-dead regions ---
    conv_kernel<<<1024, 256, 0, stream>>>(W1, W1c, D * DFF / 8);
    conv_kernel<<<1024, 256, 0, stream>>>(W2, W2c, DFF * D / 8);
    // --- 5) LN2: h2 = LN(x2) ---
    ln_kernel<<<NR, 256, 0, stream>>>(x2, ln2_g, ln2_b, h2);
    // --- 6) hff = gelu(h2 @ W1 + b1)   [4096,1024]x[1024,4096] ---
    dim3 g2(NR / 128, DFF / 128);
    gemm_kernel<2><<<g2, 256, 0, stream>>>(h2, W1c, b1, nullptr, hff, NR, DFF, D);
    // --- 7) out = x2 + hff @ W2 + b2   [4096,4096]x[4096,1024], in-place ---
    dim3 g3(NR / 128, D / 128);
    gemm_kernel<1><<<g3, 256, 0, stream>>>(hff, W2c, b2, x2, out, NR, D, DFF);
}

// Round 4
// 681.786 us; speedup vs baseline: 7.7291x; 7.7291x over previous
//
#include <hip/hip_runtime.h>
#include <hip/hip_bf16.h>
#include <math.h>

using bf16 = __hip_bfloat16;
typedef short bf16x8 __attribute__((ext_vector_type(8)));
typedef float f32x4 __attribute__((ext_vector_type(4)));

static constexpr int B = 2, S = 2048, D = 1024, H = 16, HD = 64, DFF = 4096;
static constexpr int NR = B * S; // 4096 rows
static constexpr float EPS = 1e-5f;

__device__ __forceinline__ float b2f(bf16 v) { return __bfloat162float(v); }
__device__ __forceinline__ bf16 f2b(float v) { return __float2bfloat16(v); }

// ---------------- fp32 -> bf16 converter (8 elems/thread) ----------------
__global__ __launch_bounds__(256) void conv_kernel(const float* __restrict__ src,
                                                   bf16* __restrict__ dst, int n8) {
    int i = blockIdx.x * 256 + threadIdx.x;
    const int stride = gridDim.x * 256;
    for (; i < n8; i += stride) {
        float4 a = ((const float4*)src)[2 * i];
        float4 b = ((const float4*)src)[2 * i + 1];
        union { bf16 h[8]; int4 v; } o;
        o.h[0] = f2b(a.x); o.h[1] = f2b(a.y); o.h[2] = f2b(a.z); o.h[3] = f2b(a.w);
        o.h[4] = f2b(b.x); o.h[5] = f2b(b.y); o.h[6] = f2b(b.z); o.h[7] = f2b(b.w);
        ((int4*)dst)[i] = o.v;
    }
}

// ---------------- LayerNorm: fp32 in, bf16 out; one block per row ----------------
__global__ __launch_bounds__(256) void ln_kernel(const float* __restrict__ x,
                                                 const float* __restrict__ g,
                                                 const float* __restrict__ b,
                                                 bf16* __restrict__ out) {
    const int row = blockIdx.x;
    const int tid = threadIdx.x;
    const float4 v4 = ((const float4*)(x + (size_t)row * D))[tid];
    float v[4] = {v4.x, v4.y, v4.z, v4.w};
    float s = v[0] + v[1] + v[2] + v[3];
    float sq = v[0] * v[0] + v[1] * v[1] + v[2] * v[2] + v[3] * v[3];
#pragma unroll
    for (int off = 32; off >= 1; off >>= 1) {
        s += __shfl_xor(s, off);
        sq += __shfl_xor(sq, off);
    }
    __shared__ float ssum[4], ssq[4];
    const int wave = tid >> 6;
    if ((tid & 63) == 0) { ssum[wave] = s; ssq[wave] = sq; }
    __syncthreads();
    s = ssum[0] + ssum[1] + ssum[2] + ssum[3];
    sq = ssq[0] + ssq[1] + ssq[2] + ssq[3];
    const float mu = s * (1.0f / D);
    const float var = sq * (1.0f / D) - mu * mu;
    const float rstd = rsqrtf(var + EPS);
    bf16* orow = out + (size_t)row * D;
#pragma unroll
    for (int i = 0; i < 4; ++i) {
        const int c = tid * 4 + i;
        orow[c] = f2b((v[i] - mu) * rstd * g[c] + b[c]);
    }
}

// ---------------- GEMM: C[M,N] = A[M,K] @ W[K,N] (+epilogue) ----------------
// 128x128 block tile, 4 waves 2x2, each wave 4x4 tiles of 16x16x32 bf16 MFMA.
// EPI 0: plain, bf16 out.  EPI 1: + fp32 bias + fp32 residual, fp32 out
// (res==C in-place OK).  EPI 2: + fp32 bias + exact GELU, bf16 out.
template <int EPI>
__global__ __launch_bounds__(256) void gemm_kernel(const bf16* __restrict__ A,
                                                   const bf16* __restrict__ W,
                                                   const float* __restrict__ bias,
                                                   const float* __restrict__ res,
                                                   void* __restrict__ Cv,
                                                   int M, int N, int K) {
    __shared__ __align__(16) bf16 As[128][40];   // [m][k], +8 pad
    __shared__ __align__(16) bf16 BsT[128][40];  // [n][k], +8 pad
    const int tm = blockIdx.x, tn = blockIdx.y;
    const int tid = threadIdx.x;
    const int wave = tid >> 6, lane = tid & 63;
    const int wm = wave >> 1, wn = wave & 1;
    const int quad = lane >> 4, l16 = lane & 15;

    f32x4 acc[4][4];
#pragma unroll
    for (int i = 0; i < 4; ++i)
#pragma unroll
        for (int j = 0; j < 4; ++j) acc[i][j] = (f32x4){0.f, 0.f, 0.f, 0.f};

    const int a_row = tid >> 1;        // 0..127
    const int a_c0 = (tid & 1) * 16;   // 0 or 16
    const int b_k = tid >> 3;          // 0..31
    const int b_n0 = (tid & 7) * 16;   // 0,16,..,112

    const bf16* Aptr = A + (size_t)(tm * 128 + a_row) * K + a_c0;
    const bf16* Wptr = W + (size_t)b_k * N + tn * 128 + b_n0;

    const int nk = K / 32;
    for (int kt = 0; kt < nk; ++kt) {
        __syncthreads();
        union { int4 i; bf16 h[8]; } ua0, ua1, ub0, ub1;
        ua0.i = *(const int4*)(Aptr);
        ua1.i = *(const int4*)(Aptr + 8);
        ub0.i = *(const int4*)(Wptr);
        ub1.i = *(const int4*)(Wptr + 8);
        *(int4*)&As[a_row][a_c0] = ua0.i;
        *(int4*)&As[a_row][a_c0 + 8] = ua1.i;
#pragma unroll
        for (int i = 0; i < 8; ++i) BsT[b_n0 + i][b_k] = ub0.h[i];
#pragma unroll
        for (int i = 0; i < 8; ++i) BsT[b_n0 + 8 + i][b_k] = ub1.h[i];
        __syncthreads();

        bf16x8 aF[4], bF[4];
#pragma unroll
        for (int mt = 0; mt < 4; ++mt)
            aF[mt] = *(const bf16x8*)&As[wm * 64 + mt * 16 + l16][quad * 8];
#pragma unroll
        for (int nt = 0; nt < 4; ++nt)
            bF[nt] = *(const bf16x8*)&BsT[wn * 64 + nt * 16 + l16][quad * 8];
#pragma unroll
        for (int mt = 0; mt < 4; ++mt)
#pragma unroll
            for (int nt = 0; nt < 4; ++nt)
                acc[mt][nt] = __builtin_amdgcn_mfma_f32_16x16x32_bf16(
                    aF[mt], bF[nt], acc[mt][nt], 0, 0, 0);

        Aptr += 32;
        Wptr += (size_t)32 * N;
    }

    // epilogue: C/D layout col = lane&15, row = quad*4 + j  [m89/m91-verified]
#pragma unroll
    for (int nt = 0; nt < 4; ++nt) {
        const int col = tn * 128 + wn * 64 + nt * 16 + l16;
        float bv = 0.f;
        if (EPI != 0) bv = bias[col];
#pragma unroll
        for (int mt = 0; mt < 4; ++mt) {
            const int row0 = tm * 128 + wm * 64 + mt * 16 + quad * 4;
#pragma unroll
            for (int j = 0; j < 4; ++j) {
                float v = acc[mt][nt][j];
                const size_t idx = (size_t)(row0 + j) * N + col;
                if (EPI == 1) {
                    v += bv + res[idx];
                    ((float*)Cv)[idx] = v;
                } else if (EPI == 2) {
                    v += bv;
                    v = 0.5f * v * (1.0f + erff(v * 0.70710678118654752f));
                    ((bf16*)Cv)[idx] = f2b(v);
                } else {
                    ((bf16*)Cv)[idx] = f2b(v);
                }
            }
        }
    }
}

// ---------------- MFMA flash attention (causal) ----------------
// Grid (S/64, B*H). Block: 64-query tile, 4 waves x 16 rows. K/V chunks of 64.
// Layouts (m89/m91/m120-verified):
//   A-frag:  A[m = lane&15][k = quad*8 + j]
//   B-frag:  B[k = quad*8 + j][n = lane&15]
//   C/D:     col = lane&15, row = quad*4 + j
__global__ __launch_bounds__(256) void fattn_kernel(const bf16* __restrict__ Q,
                                                    const bf16* __restrict__ K,
                                                    const bf16* __restrict__ V,
                                                    bf16* __restrict__ ctx) {
    const int t = blockIdx.x;       // query tile
    const int bh = blockIdx.y;
    const int b = bh / H, h = bh % H;
    const int tid = threadIdx.x;
    const int wave = tid >> 6, lane = tid & 63;
    const int quad = lane >> 4, l16 = lane & 15;
    const size_t headoff = (size_t)b * S * D + (size_t)h * HD;
    const int q0 = t * 64;

    __shared__ __align__(16) bf16 Ks[64][72];  // [key][d]
    __shared__ __align__(16) bf16 Vt[64][72];  // [d][key]  (transposed)
    __shared__ __align__(16) bf16 Ps[64][72];  // [wave*16+row][key] wave-private

    // Q fragments (A-layout), loaded once
    const bf16* qp = Q + headoff + (size_t)(q0 + wave * 16 + l16) * D + quad * 8;
    const bf16x8 aQ0 = *(const bf16x8*)(qp);
    const bf16x8 aQ1 = *(const bf16x8*)(qp + 32);

    f32x4 O[4];
#pragma unroll
    for (int nt = 0; nt < 4; ++nt) O[nt] = (f32x4){0.f, 0.f, 0.f, 0.f};
    float m[4] = {-3.0e38f, -3.0e38f, -3.0e38f, -3.0e38f};
    float l[4] = {0.f, 0.f, 0.f, 0.f};

    const int s_key = tid >> 2;        // 0..63
    const int s_d0 = (tid & 3) * 16;   // 0,16,32,48

    const int nchunks = t + 1;
    for (int c = 0; c < nchunks; ++c) {
        const int k0 = c * 64;
        __syncthreads();
        // stage K [key][d]
        const bf16* kg = K + headoff + (size_t)(k0 + s_key) * D + s_d0;
        int4 k4a = *(const int4*)kg;
        int4 k4b = *(const int4*)(kg + 8);
        *(int4*)&Ks[s_key][s_d0] = k4a;
        *(int4*)&Ks[s_key][s_d0 + 8] = k4b;
        // stage V transposed [d][key]
        const bf16* vg = V + headoff + (size_t)(k0 + s_key) * D + s_d0;
        union { int4 v; bf16 hh[8]; } uv0, uv1;
        uv0.v = *(const int4*)vg;
        uv1.v = *(const int4*)(vg + 8);
#pragma unroll
        for (int i = 0; i < 8; ++i) Vt[s_d0 + i][s_key] = uv0.hh[i];
#pragma unroll
        for (int i = 0; i < 8; ++i) Vt[s_d0 + 8 + i][s_key] = uv1.hh[i];
        __syncthreads();

        // scores: S = Q K^T  (16q x 64k per wave), scaled by 1/sqrt(64)
        f32x4 sc[4];
#pragma unroll
        for (int nt = 0; nt < 4; ++nt) {
            const bf16x8 bK0 = *(const bf16x8*)&Ks[nt * 16 + l16][quad * 8];
            const bf16x8 bK1 = *(const bf16x8*)&Ks[nt * 16 + l16][32 + quad * 8];
            f32x4 z = (f32x4){0.f, 0.f, 0.f, 0.f};
            z = __builtin_amdgcn_mfma_f32_16x16x32_bf16(aQ0, bK0, z, 0, 0, 0);
            z = __builtin_amdgcn_mfma_f32_16x16x32_bf16(aQ1, bK1, z, 0, 0, 0);
            sc[nt] = z;
        }
#pragma unroll
        for (int nt = 0; nt < 4; ++nt)
#pragma unroll
            for (int j = 0; j < 4; ++j) sc[nt][j] *= 0.125f;
        // causal mask — only the diagonal chunk (k0 == q0 there)
        if (c == nchunks - 1) {
#pragma unroll
            for (int nt = 0; nt < 4; ++nt) {
                const int key_l = nt * 16 + l16;
#pragma unroll
                for (int j = 0; j < 4; ++j)
                    if (key_l > wave * 16 + quad * 4 + j) sc[nt][j] = -3.0e38f;
            }
        }
        // online softmax per query row (rows = quad*4+j; reduce over 16 lanes)
        float al[4];
#pragma unroll
        for (int j = 0; j < 4; ++j) {
            float mx = fmaxf(fmaxf(sc[0][j], sc[1][j]), fmaxf(sc[2][j], sc[3][j]));
#pragma unroll
            for (int off = 1; off <= 8; off <<= 1) mx = fmaxf(mx, __shfl_xor(mx, off));
            const float mn = fmaxf(m[j], mx);
            al[j] = __expf(m[j] - mn);
            m[j] = mn;
            float rs = 0.f;
#pragma unroll
            for (int nt = 0; nt < 4; ++nt) {
                sc[nt][j] = __expf(sc[nt][j] - mn);
                rs += sc[nt][j];
            }
#pragma unroll
            for (int off = 1; off <= 8; off <<= 1) rs += __shfl_xor(rs, off);
            l[j] = l[j] * al[j] + rs;
        }
        // P: C-layout -> LDS -> A-layout (wave-private region)
#pragma unroll
        for (int nt = 0; nt < 4; ++nt)
#pragma unroll
            for (int j = 0; j < 4; ++j)
                Ps[wave * 16 + quad * 4 + j][nt * 16 + l16] = f2b(sc[nt][j]);
        asm volatile("s_waitcnt lgkmcnt(0)" ::: "memory");
        const bf16x8 aP0 = *(const bf16x8*)&Ps[wave * 16 + l16][quad * 8];
        const bf16x8 aP1 = *(const bf16x8*)&Ps[wave * 16 + l16][32 + quad * 8];
        // O = O*alpha + P V
#pragma unroll
        for (int nt = 0; nt < 4; ++nt)
#pragma unroll
            for (int j = 0; j < 4; ++j) O[nt][j] *= al[j];
#pragma unroll
        for (int nt = 0; nt < 4; ++nt) {
            const bf16x8 bV0 = *(const bf16x8*)&Vt[nt * 16 + l16][quad * 8];
            const bf16x8 bV1 = *(const bf16x8*)&Vt[nt * 16 + l16][32 + quad * 8];
            O[nt] = __builtin_amdgcn_mfma_f32_16x16x32_bf16(aP0, bV0, O[nt], 0, 0, 0);
            O[nt] = __builtin_amdgcn_mfma_f32_16x16x32_bf16(aP1, bV1, O[nt], 0, 0, 0);
        }
    }

    // finalize: ctx[token][h*64 + d]
    float rl[4];
#pragma unroll
    for (int j = 0; j < 4; ++j) rl[j] = 1.0f / l[j];
#pragma unroll
    for (int nt = 0; nt < 4; ++nt)
#pragma unroll
        for (int j = 0; j < 4; ++j)
            ctx[headoff + (size_t)(q0 + wave * 16 + quad * 4 + j) * D + nt * 16 + l16] =
                f2b(O[nt][j] * rl[j]);
}

// ---------------- launcher ----------------
extern "C" void kernel_launch(void* const* d_in, const int* in_sizes, int n_in,
                              void* d_out, int out_size, void* d_ws, size_t ws_size,
                              hipStream_t stream) {
    const float* x     = (const float*)d_in[0];
    const float* ln1_g = (const float*)d_in[1];
    const float* ln1_b = (const float*)d_in[2];
    const float* Wq    = (const float*)d_in[3];
    const float* Wk    = (const float*)d_in[4];
    const float* Wv    = (const float*)d_in[5];
    const float* Wo    = (const float*)d_in[6];
    const float* bo    = (const float*)d_in[7];
    const float* ln2_g = (const float*)d_in[8];
    const float* ln2_b = (const float*)d_in[9];
    const float* W1    = (const float*)d_in[10];
    const float* b1    = (const float*)d_in[11];
    const float* W2    = (const float*)d_in[12];
    const float* b2    = (const float*)d_in[13];
    float* out = (float*)d_out;

    // workspace layout (MB), lifetime-overlapped; peak 56 MB:
    //   [ 0, 8): h (LN1 out, bf16) -> ctx (attn out) -> W1c (bf16)
    //   [ 8,16): Qb (bf16)         -> h2 (LN2 out, bf16)
    //   [16,24): Kb (bf16)  \
    //   [24,32): Vb (bf16)   }     -> hff [16,48) (bf16, 32 MB)
    //   [32,48): (hff tail)
    //   [48,56): Wqc/Wkc/Wvc/Woc (2 MB each) -> W2c (bf16, 8 MB)
    //   x2 (fp32 residual stream) lives in d_out; final GEMM reads in-place.
    char* ws = (char*)d_ws;
    const size_t MB = (size_t)1 << 20;
    bf16* h   = (bf16*)(ws + 0 * MB);
    bf16* ctx = (bf16*)(ws + 0 * MB);
    bf16* W1c = (bf16*)(ws + 0 * MB);
    bf16* Qb  = (bf16*)(ws + 8 * MB);
    bf16* h2  = (bf16*)(ws + 8 * MB);
    bf16* Kb  = (bf16*)(ws + 16 * MB);
    bf16* Vb  = (bf16*)(ws + 24 * MB);
    bf16* hff = (bf16*)(ws + 16 * MB);
    bf16* Wqc = (bf16*)(ws + 48 * MB);
    bf16* Wkc = (bf16*)(ws + 50 * MB);
    bf16* Wvc = (bf16*)(ws + 52 * MB);
    bf16* Woc = (bf16*)(ws + 54 * MB);
    bf16* W2c = (bf16*)(ws + 48 * MB);
    float* x2 = out;

    // --- 0) convert attention weights to bf16 ---
    conv_kernel<<<512, 256, 0, stream>>>(Wq, Wqc, D * D / 8);
    conv_kernel<<<512, 256, 0, stream>>>(Wk, Wkc, D * D / 8);
    conv_kernel<<<512, 256, 0, stream>>>(Wv, Wvc, D * D / 8);
    conv_kernel<<<512, 256, 0, stream>>>(Wo, Woc, D * D / 8);
    // --- 1) LN1: h = LN(x) ---
    ln_kernel<<<NR, 256, 0, stream>>>(x, ln1_g, ln1_b, h);
    // --- 2) Q,K,V = h @ W{q,k,v} ---
    dim3 g1(NR / 128, D / 128);
    gemm_kernel<0><<<g1, 256, 0, stream>>>(h, Wqc, nullptr, nullptr, Qb, NR, D, D);
    gemm_kernel<0><<<g1, 256, 0, stream>>>(h, Wkc, nullptr, nullptr, Kb, NR, D, D);
    gemm_kernel<0><<<g1, 256, 0, stream>>>(h, Wvc, nullptr, nullptr, Vb, NR, D, D);
    // --- 3) MFMA flash attention -> ctx (over dead h) ---
    dim3 ga(S / 64, B * H);
    fattn_kernel<<<ga, 256, 0, stream>>>(Qb, Kb, Vb, ctx);
    // --- 4) x2 = x + ctx @ Wo + bo  (fp32, into d_out) ---
    gemm_kernel<1><<<g1, 256, 0, stream>>>(ctx, Woc, bo, x, x2, NR, D, D);
    // --- convert MLP weights into now-dead regions ---
    conv_kernel<<<1024, 256, 0, stream>>>(W1, W1c, D * DFF / 8);
    conv_kernel<<<1024, 256, 0, stream>>>(W2, W2c, DFF * D / 8);
    // --- 5) LN2: h2 = LN(x2) ---
    ln_kernel<<<NR, 256, 0, stream>>>(x2, ln2_g, ln2_b, h2);
    // --- 6) hff = gelu(h2 @ W1 + b1) ---
    dim3 g2(NR / 128, DFF / 128);
    gemm_kernel<2><<<g2, 256, 0, stream>>>(h2, W1c, b1, nullptr, hff, NR, DFF, D);
    // --- 7) out = x2 + hff @ W2 + b2  (in-place residual) ---
    dim3 g3(NR / 128, D / 128);
    gemm_kernel<1><<<g3, 256, 0, stream>>>(hff, W2c, b2, x2, out, NR, D, DFF);
}

// Round 5
// 472.263 us; speedup vs baseline: 11.1582x; 1.4437x over previous
//
#include <hip/hip_runtime.h>
#include <hip/hip_bf16.h>
#include <math.h>

using bf16 = __hip_bfloat16;
typedef short bf16x8 __attribute__((ext_vector_type(8)));
typedef float f32x4 __attribute__((ext_vector_type(4)));

static constexpr int B = 2, S = 2048, D = 1024, H = 16, HD = 64, DFF = 4096;
static constexpr int NR = B * S;   // 4096 rows
static constexpr int DQ = 3072;    // packed QKV row stride
static constexpr float EPS = 1e-5f;

__device__ __forceinline__ bf16 f2b(float v) { return __float2bfloat16(v); }

// async global->LDS, 16B per lane; LDS dest must be wave-uniform base + lane*16
typedef __attribute__((address_space(1))) const void* gp1_t;
typedef __attribute__((address_space(3))) void* sp3_t;
__device__ __forceinline__ void gld_lds16(const bf16* g, bf16* l) {
    __builtin_amdgcn_global_load_lds((gp1_t)(const void*)g, (sp3_t)(void*)l, 16, 0, 0);
}

// ---------------- tiled transpose + fp32->bf16: dst[n][k] = src[k][n] ----------------
__global__ __launch_bounds__(256) void convT_kernel(const float* __restrict__ src, // [K][N]
                                                    bf16* __restrict__ dst,        // [N][K]
                                                    int K, int N) {
    __shared__ float tile[64][65];
    const int k0 = blockIdx.x * 64, n0 = blockIdx.y * 64;
    const int tid = threadIdx.x;
    const int r = tid >> 4, c = (tid & 15) * 4;
#pragma unroll
    for (int rr = 0; rr < 64; rr += 16) {
        float4 v = *(const float4*)&src[(size_t)(k0 + r + rr) * N + n0 + c];
        tile[r + rr][c] = v.x; tile[r + rr][c + 1] = v.y;
        tile[r + rr][c + 2] = v.z; tile[r + rr][c + 3] = v.w;
    }
    __syncthreads();
    const int n = tid >> 2, ks = (tid & 3) * 16;
    union { bf16 h[16]; int4 v2[2]; } o;
#pragma unroll
    for (int i = 0; i < 16; ++i) o.h[i] = f2b(tile[ks + i][n]);
    bf16* dp = &dst[(size_t)(n0 + n) * K + k0 + ks];
    *(int4*)dp = o.v2[0];
    *(int4*)(dp + 8) = o.v2[1];
}

// ---------------- LayerNorm: fp32 in, bf16 out; one block per row ----------------
__global__ __launch_bounds__(256) void ln_kernel(const float* __restrict__ x,
                                                 const float* __restrict__ g,
                                                 const float* __restrict__ b,
                                                 bf16* __restrict__ out) {
    const int row = blockIdx.x;
    const int tid = threadIdx.x;
    const float4 v4 = ((const float4*)(x + (size_t)row * D))[tid];
    float v[4] = {v4.x, v4.y, v4.z, v4.w};
    float s = v[0] + v[1] + v[2] + v[3];
    float sq = v[0] * v[0] + v[1] * v[1] + v[2] * v[2] + v[3] * v[3];
#pragma unroll
    for (int off = 32; off >= 1; off >>= 1) {
        s += __shfl_xor(s, off);
        sq += __shfl_xor(sq, off);
    }
    __shared__ float ssum[4], ssq[4];
    const int wave = tid >> 6;
    if ((tid & 63) == 0) { ssum[wave] = s; ssq[wave] = sq; }
    __syncthreads();
    s = ssum[0] + ssum[1] + ssum[2] + ssum[3];
    sq = ssq[0] + ssq[1] + ssq[2] + ssq[3];
    const float mu = s * (1.0f / D);
    const float var = sq * (1.0f / D) - mu * mu;
    const float rstd = rsqrtf(var + EPS);
    bf16* orow = out + (size_t)row * D;
#pragma unroll
    for (int i = 0; i < 4; ++i) {
        const int c = tid * 4 + i;
        orow[c] = f2b((v[i] - mu) * rstd * g[c] + b[c]);
    }
}

// ---------------- GEMM (m97 structure): C[M,N] = A[M,K] @ Bt[N,K]^T ----------------
// 128 x BN tile, 4 waves 2x2. All staging via global_load_lds (16B, lane-ordered
// contiguous LDS). EPI 0: bf16 out. EPI 1: + fp32 bias + fp32 residual, fp32 out
// (res==C in-place OK). EPI 2: + fp32 bias + exact GELU, bf16 out.
template <int EPI, int BN>
__global__ __launch_bounds__(256) void gemm_bt(const bf16* __restrict__ A,
                                               const bf16* __restrict__ Bt,
                                               const float* __restrict__ bias,
                                               const float* __restrict__ res,
                                               void* __restrict__ Cv,
                                               int M, int N, int K) {
    constexpr int NT = BN / 32;               // n-tiles per wave
    __shared__ __align__(16) bf16 As[128 * 32];
    __shared__ __align__(16) bf16 Bs[BN * 32];
    const int tm = blockIdx.x, tn = blockIdx.y;
    const int tid = threadIdx.x;
    const int wave = tid >> 6, lane = tid & 63;
    const int wm = wave >> 1, wn = wave & 1;
    const int quad = lane >> 4, l16 = lane & 15;

    f32x4 acc[4][NT];
#pragma unroll
    for (int i = 0; i < 4; ++i)
#pragma unroll
        for (int j = 0; j < NT; ++j) acc[i][j] = (f32x4){0.f, 0.f, 0.f, 0.f};

    // slot s (16B) <-> (row = s>>2, kseg = (s&3)*8); LDS byte offset = s*16
    const int s_row = tid >> 2, s_seg = (tid & 3) * 8;
    const bf16* Ap = A + (size_t)(tm * 128 + s_row) * K + s_seg;
    const bf16* Bp = Bt + (size_t)(tn * BN + s_row) * K + s_seg;
    const size_t K64 = (size_t)64 * K;
    bf16* lA0 = As + tid * 8;
    bf16* lA1 = As + (256 + tid) * 8;
    bf16* lB0 = Bs + tid * 8;

    const int nk = K / 32;
    for (int kt = 0; kt < nk; ++kt) {
        __syncthreads();
        gld_lds16(Ap, lA0);
        gld_lds16(Ap + K64, lA1);
        gld_lds16(Bp, lB0);
        if constexpr (BN == 128) {
            gld_lds16(Bp + K64, Bs + (256 + tid) * 8);
        }
        __syncthreads();

        bf16x8 aF[4], bF[NT];
#pragma unroll
        for (int mt = 0; mt < 4; ++mt)
            aF[mt] = *(const bf16x8*)(As + (wm * 64 + mt * 16 + l16) * 32 + quad * 8);
#pragma unroll
        for (int nt = 0; nt < NT; ++nt)
            bF[nt] = *(const bf16x8*)(Bs + (wn * (BN / 2) + nt * 16 + l16) * 32 + quad * 8);
#pragma unroll
        for (int mt = 0; mt < 4; ++mt)
#pragma unroll
            for (int nt = 0; nt < NT; ++nt)
                acc[mt][nt] = __builtin_amdgcn_mfma_f32_16x16x32_bf16(
                    aF[mt], bF[nt], acc[mt][nt], 0, 0, 0);

        Ap += 32;
        Bp += 32;
    }

    // epilogue: C/D layout col = lane&15, row = quad*4 + j  [m89/m91-verified]
#pragma unroll
    for (int nt = 0; nt < NT; ++nt) {
        const int col = tn * BN + wn * (BN / 2) + nt * 16 + l16;
        float bv = 0.f;
        if (EPI != 0) bv = bias[col];
#pragma unroll
        for (int mt = 0; mt < 4; ++mt) {
            const int row0 = tm * 128 + wm * 64 + mt * 16 + quad * 4;
#pragma unroll
            for (int j = 0; j < 4; ++j) {
                float v = acc[mt][nt][j];
                const size_t idx = (size_t)(row0 + j) * N + col;
                if (EPI == 1) {
                    v += bv + res[idx];
                    ((float*)Cv)[idx] = v;
                } else if (EPI == 2) {
                    v += bv;
                    v = 0.5f * v * (1.0f + erff(v * 0.70710678118654752f));
                    ((bf16*)Cv)[idx] = f2b(v);
                } else {
                    ((bf16*)Cv)[idx] = f2b(v);
                }
            }
        }
    }
}

// ---------------- MFMA flash attention (causal), packed QKV input ----------------
// Grid (S/64, B*H); big-t tiles first. 64-query tile, 4 waves x 16 rows, 64-key chunks.
// K staged via global_load_lds into XOR-swizzled slots: slot = key*8 + (dseg ^ (key&7)).
// V^T staged lane-major-key (bank = d*4 + key/2, key spans 64 -> conflict-free).
__global__ __launch_bounds__(256) void fattn_kernel(const bf16* __restrict__ QKV,
                                                    bf16* __restrict__ ctx) {
    const int t = (int)gridDim.x - 1 - (int)blockIdx.x;
    const int bh = blockIdx.y;
    const int b = bh >> 4, h = bh & (H - 1);
    const int tid = threadIdx.x;
    const int wave = tid >> 6, lane = tid & 63;
    const int quad = lane >> 4, l16 = lane & 15;
    const bf16* Qp = QKV + (size_t)b * S * DQ + h * HD;
    const bf16* Kp = Qp + D;
    const bf16* Vp = Qp + 2 * D;
    const int q0 = t * 64;

    __shared__ __align__(16) bf16 Ks[64 * 64];   // swizzled [key][dseg]
    __shared__ __align__(16) bf16 Vt[64][72];    // [d][key]
    __shared__ __align__(16) bf16 Ps[64][72];    // [q][key], wave-private rows

    // Q fragments (A-layout), loaded once
    const bf16* qg = Qp + (size_t)(q0 + wave * 16 + l16) * DQ + quad * 8;
    const bf16x8 aQ0 = *(const bf16x8*)(qg);
    const bf16x8 aQ1 = *(const bf16x8*)(qg + 32);

    f32x4 O[4];
#pragma unroll
    for (int nt = 0; nt < 4; ++nt) O[nt] = (f32x4){0.f, 0.f, 0.f, 0.f};
    float m[4] = {-3.0e38f, -3.0e38f, -3.0e38f, -3.0e38f};
    float l[4] = {0.f, 0.f, 0.f, 0.f};

    // K staging slots (2 per thread)
    const int keyA = tid >> 3, dsA = ((tid & 7) ^ (keyA & 7)) * 8;
    const int sB = 256 + tid;
    const int keyB = sB >> 3, dsB = ((sB & 7) ^ (keyB & 7)) * 8;
    bf16* lKA = Ks + tid * 8;
    bf16* lKB = Ks + sB * 8;

    for (int c = 0; c <= t; ++c) {
        const int k0 = c * 64;
        __syncthreads();
        // K: async direct-to-LDS
        gld_lds16(Kp + (size_t)(k0 + keyA) * DQ + dsA, lKA);
        gld_lds16(Kp + (size_t)(k0 + keyB) * DQ + dsB, lKB);
        // V: transpose-stage, lane-major key
        const bf16* vg = Vp + (size_t)(k0 + lane) * DQ + wave * 16;
        union { int4 v; bf16 hh[8]; } uv0, uv1;
        uv0.v = *(const int4*)vg;
        uv1.v = *(const int4*)(vg + 8);
#pragma unroll
        for (int i = 0; i < 8; ++i) Vt[wave * 16 + i][lane] = uv0.hh[i];
#pragma unroll
        for (int i = 0; i < 8; ++i) Vt[wave * 16 + 8 + i][lane] = uv1.hh[i];
        __syncthreads();

        // scores: 16q x 64k per wave, scaled by 1/sqrt(64)
        f32x4 sc[4];
#pragma unroll
        for (int nt = 0; nt < 4; ++nt) {
            const int r = nt * 16 + l16;
            const bf16x8 bK0 = *(const bf16x8*)(Ks + (r * 8 + (quad ^ (r & 7))) * 8);
            const bf16x8 bK1 = *(const bf16x8*)(Ks + (r * 8 + ((4 + quad) ^ (r & 7))) * 8);
            f32x4 z = (f32x4){0.f, 0.f, 0.f, 0.f};
            z = __builtin_amdgcn_mfma_f32_16x16x32_bf16(aQ0, bK0, z, 0, 0, 0);
            z = __builtin_amdgcn_mfma_f32_16x16x32_bf16(aQ1, bK1, z, 0, 0, 0);
            sc[nt] = z;
        }
#pragma unroll
        for (int nt = 0; nt < 4; ++nt)
#pragma unroll
            for (int j = 0; j < 4; ++j) sc[nt][j] *= 0.125f;
        // causal mask — only the diagonal chunk (k0 == q0)
        if (c == t) {
#pragma unroll
            for (int nt = 0; nt < 4; ++nt) {
                const int key_l = nt * 16 + l16;
#pragma unroll
                for (int j = 0; j < 4; ++j)
                    if (key_l > wave * 16 + quad * 4 + j) sc[nt][j] = -3.0e38f;
            }
        }
        // online softmax (rows = quad*4+j; reduce across 16 lanes)
        float al[4];
#pragma unroll
        for (int j = 0; j < 4; ++j) {
            float mx = fmaxf(fmaxf(sc[0][j], sc[1][j]), fmaxf(sc[2][j], sc[3][j]));
#pragma unroll
            for (int off = 1; off <= 8; off <<= 1) mx = fmaxf(mx, __shfl_xor(mx, off));
            const float mn = fmaxf(m[j], mx);
            al[j] = __expf(m[j] - mn);
            m[j] = mn;
            float rs = 0.f;
#pragma unroll
            for (int nt = 0; nt < 4; ++nt) {
                sc[nt][j] = __expf(sc[nt][j] - mn);
                rs += sc[nt][j];
            }
#pragma unroll
            for (int off = 1; off <= 8; off <<= 1) rs += __shfl_xor(rs, off);
            l[j] = l[j] * al[j] + rs;
        }
        // P: C-layout -> LDS -> A-layout (wave-private rows)
#pragma unroll
        for (int nt = 0; nt < 4; ++nt)
#pragma unroll
            for (int j = 0; j < 4; ++j)
                Ps[wave * 16 + quad * 4 + j][nt * 16 + l16] = f2b(sc[nt][j]);
        asm volatile("s_waitcnt lgkmcnt(0)" ::: "memory");
        const bf16x8 aP0 = *(const bf16x8*)&Ps[wave * 16 + l16][quad * 8];
        const bf16x8 aP1 = *(const bf16x8*)&Ps[wave * 16 + l16][32 + quad * 8];
        // O = O*alpha + P V
#pragma unroll
        for (int nt = 0; nt < 4; ++nt)
#pragma unroll
            for (int j = 0; j < 4; ++j) O[nt][j] *= al[j];
#pragma unroll
        for (int nt = 0; nt < 4; ++nt) {
            const bf16x8 bV0 = *(const bf16x8*)&Vt[nt * 16 + l16][quad * 8];
            const bf16x8 bV1 = *(const bf16x8*)&Vt[nt * 16 + l16][32 + quad * 8];
            O[nt] = __builtin_amdgcn_mfma_f32_16x16x32_bf16(aP0, bV0, O[nt], 0, 0, 0);
            O[nt] = __builtin_amdgcn_mfma_f32_16x16x32_bf16(aP1, bV1, O[nt], 0, 0, 0);
        }
    }

    // finalize: ctx compact [token][h*64+d], stride D
    const size_t hoC = (size_t)b * S * D + h * HD;
    float rl[4];
#pragma unroll
    for (int j = 0; j < 4; ++j) rl[j] = 1.0f / l[j];
#pragma unroll
    for (int nt = 0; nt < 4; ++nt)
#pragma unroll
        for (int j = 0; j < 4; ++j)
            ctx[hoC + (size_t)(q0 + wave * 16 + quad * 4 + j) * D + nt * 16 + l16] =
                f2b(O[nt][j] * rl[j]);
}

// ---------------- launcher ----------------
extern "C" void kernel_launch(void* const* d_in, const int* in_sizes, int n_in,
                              void* d_out, int out_size, void* d_ws, size_t ws_size,
                              hipStream_t stream) {
    const float* x     = (const float*)d_in[0];
    const float* ln1_g = (const float*)d_in[1];
    const float* ln1_b = (const float*)d_in[2];
    const float* Wq    = (const float*)d_in[3];
    const float* Wk    = (const float*)d_in[4];
    const float* Wv    = (const float*)d_in[5];
    const float* Wo    = (const float*)d_in[6];
    const float* bo    = (const float*)d_in[7];
    const float* ln2_g = (const float*)d_in[8];
    const float* ln2_b = (const float*)d_in[9];
    const float* W1    = (const float*)d_in[10];
    const float* b1    = (const float*)d_in[11];
    const float* W2    = (const float*)d_in[12];
    const float* b2    = (const float*)d_in[13];
    float* out = (float*)d_out;

    // workspace (MB), lifetime-overlapped; peak exactly 64 MB:
    //   [ 0, 8): h (LN1 out)            -> W1T (conv after QKV gemm)
    //   [ 8,32): QKVb (packed, 24 MB)   \
    //   [32,40): ctx (attn out)          } -> hff [8,40) (32 MB)
    //   [40,48): h2 (LN2 out)
    //   [48,54): WqkvT   [54,56): WoT   [56,64): W2T
    //   x2 (fp32 residual) lives in d_out; final GEMM reads it in-place.
    char* ws = (char*)d_ws;
    const size_t MB = (size_t)1 << 20;
    bf16* h     = (bf16*)(ws + 0 * MB);
    bf16* W1T   = (bf16*)(ws + 0 * MB);
    bf16* QKVb  = (bf16*)(ws + 8 * MB);
    bf16* hff   = (bf16*)(ws + 8 * MB);
    bf16* ctx   = (bf16*)(ws + 32 * MB);
    bf16* h2    = (bf16*)(ws + 40 * MB);
    bf16* WqkvT = (bf16*)(ws + 48 * MB);
    bf16* WoT   = (bf16*)(ws + 54 * MB);
    bf16* W2T   = (bf16*)(ws + 56 * MB);

    // --- 0) transpose-convert weights (Wq/Wk/Wv fused into one B^T) ---
    dim3 gt(16, 16);
    convT_kernel<<<gt, 256, 0, stream>>>(Wq, WqkvT,                 D, D);
    convT_kernel<<<gt, 256, 0, stream>>>(Wk, WqkvT + (size_t)D * D, D, D);
    convT_kernel<<<gt, 256, 0, stream>>>(Wv, WqkvT + (size_t)2 * D * D, D, D);
    convT_kernel<<<gt, 256, 0, stream>>>(Wo, WoT, D, D);
    convT_kernel<<<dim3(64, 16), 256, 0, stream>>>(W2, W2T, DFF, D);
    // --- 1) LN1 ---
    ln_kernel<<<NR, 256, 0, stream>>>(x, ln1_g, ln1_b, h);
    // --- 2) QKV = h @ [Wq|Wk|Wv]   [4096,1024]x[1024,3072] ---
    gemm_bt<0, 128><<<dim3(NR / 128, DQ / 128), 256, 0, stream>>>(
        h, WqkvT, nullptr, nullptr, QKVb, NR, DQ, D);
    // h dead now -> W1T into [0,8)
    convT_kernel<<<dim3(16, 64), 256, 0, stream>>>(W1, W1T, D, DFF);
    // --- 3) flash attention -> ctx ---
    fattn_kernel<<<dim3(S / 64, B * H), 256, 0, stream>>>(QKVb, ctx);
    // --- 4) x2 = x + ctx @ Wo + bo   (fp32 into d_out) ---
    gemm_bt<1, 64><<<dim3(NR / 128, D / 64), 256, 0, stream>>>(
        ctx, WoT, bo, x, out, NR, D, D);
    // --- 5) LN2 ---
    ln_kernel<<<NR, 256, 0, stream>>>(out, ln2_g, ln2_b, h2);
    // --- 6) hff = gelu(h2 @ W1 + b1)   [4096,1024]x[1024,4096] ---
    gemm_bt<2, 128><<<dim3(NR / 128, DFF / 128), 256, 0, stream>>>(
        h2, W1T, b1, nullptr, hff, NR, DFF, D);
    // --- 7) out = x2 + hff @ W2 + b2   [4096,4096]x[4096,1024], in-place ---
    gemm_bt<1, 64><<<dim3(NR / 128, D / 64), 256, 0, stream>>>(
        hff, W2T, b2, out, out, NR, D, DFF);
}

// Round 6
// 438.942 us; speedup vs baseline: 12.0053x; 1.0759x over previous
//
#include <hip/hip_runtime.h>
#include <hip/hip_bf16.h>
#include <math.h>

using bf16 = __hip_bfloat16;
typedef short bf16x8 __attribute__((ext_vector_type(8)));
typedef float f32x4 __attribute__((ext_vector_type(4)));

static constexpr int B = 2, S = 2048, D = 1024, H = 16, HD = 64, DFF = 4096;
static constexpr int NR = B * S;   // 4096 rows
static constexpr int DQ = 3072;    // packed QKV row stride
static constexpr float EPS = 1e-5f;

__device__ __forceinline__ bf16 f2b(float v) { return __float2bfloat16(v); }

// async global->LDS, 16B per lane; LDS dest must be wave-uniform base + lane*16
typedef __attribute__((address_space(1))) const void* gp1_t;
typedef __attribute__((address_space(3))) void* sp3_t;
__device__ __forceinline__ void gld_lds16(const bf16* g, bf16* l) {
    __builtin_amdgcn_global_load_lds((gp1_t)(const void*)g, (sp3_t)(void*)l, 16, 0, 0);
}

// ---------------- tiled transpose + fp32->bf16: dst[n][k] = src[k][n] ----------------
__global__ __launch_bounds__(256) void convT_kernel(const float* __restrict__ src, // [K][N]
                                                    bf16* __restrict__ dst,        // [N][K]
                                                    int K, int N) {
    __shared__ float tile[64][65];
    const int k0 = blockIdx.x * 64, n0 = blockIdx.y * 64;
    const int tid = threadIdx.x;
    const int r = tid >> 4, c = (tid & 15) * 4;
#pragma unroll
    for (int rr = 0; rr < 64; rr += 16) {
        float4 v = *(const float4*)&src[(size_t)(k0 + r + rr) * N + n0 + c];
        tile[r + rr][c] = v.x; tile[r + rr][c + 1] = v.y;
        tile[r + rr][c + 2] = v.z; tile[r + rr][c + 3] = v.w;
    }
    __syncthreads();
    const int n = tid >> 2, ks = (tid & 3) * 16;
    union { bf16 h[16]; int4 v2[2]; } o;
#pragma unroll
    for (int i = 0; i < 16; ++i) o.h[i] = f2b(tile[ks + i][n]);
    bf16* dp = &dst[(size_t)(n0 + n) * K + k0 + ks];
    *(int4*)dp = o.v2[0];
    *(int4*)(dp + 8) = o.v2[1];
}

// ---------------- LayerNorm: fp32 in, bf16 out; one block per row ----------------
__global__ __launch_bounds__(256) void ln_kernel(const float* __restrict__ x,
                                                 const float* __restrict__ g,
                                                 const float* __restrict__ b,
                                                 bf16* __restrict__ out) {
    const int row = blockIdx.x;
    const int tid = threadIdx.x;
    const float4 v4 = ((const float4*)(x + (size_t)row * D))[tid];
    float v[4] = {v4.x, v4.y, v4.z, v4.w};
    float s = v[0] + v[1] + v[2] + v[3];
    float sq = v[0] * v[0] + v[1] * v[1] + v[2] * v[2] + v[3] * v[3];
#pragma unroll
    for (int off = 32; off >= 1; off >>= 1) {
        s += __shfl_xor(s, off);
        sq += __shfl_xor(sq, off);
    }
    __shared__ float ssum[4], ssq[4];
    const int wave = tid >> 6;
    if ((tid & 63) == 0) { ssum[wave] = s; ssq[wave] = sq; }
    __syncthreads();
    s = ssum[0] + ssum[1] + ssum[2] + ssum[3];
    sq = ssq[0] + ssq[1] + ssq[2] + ssq[3];
    const float mu = s * (1.0f / D);
    const float var = sq * (1.0f / D) - mu * mu;
    const float rstd = rsqrtf(var + EPS);
    bf16* orow = out + (size_t)row * D;
#pragma unroll
    for (int i = 0; i < 4; ++i) {
        const int c = tid * 4 + i;
        orow[c] = f2b((v[i] - mu) * rstd * g[c] + b[c]);
    }
}

// ---------------- GEMM (m97 structure): C[M,N] = A[M,K] @ Bt[N,K]^T ----------------
// Grid: blockIdx.x = n-tile (fast; consecutive blocks share the A strip -> L2 reuse),
// blockIdx.y = m-tile. 128 x BN tile, 4 waves 2x2, global_load_lds staging.
// EPI 0: bf16 out. EPI 1: + fp32 bias + fp32 residual, fp32 out (res==C OK).
// EPI 2: + fp32 bias + exact GELU, bf16 out.
template <int EPI, int BN>
__global__ __launch_bounds__(256) void gemm_bt(const bf16* __restrict__ A,
                                               const bf16* __restrict__ Bt,
                                               const float* __restrict__ bias,
                                               const float* __restrict__ res,
                                               void* __restrict__ Cv,
                                               int M, int N, int K) {
    constexpr int NT = BN / 32;               // n-tiles per wave
    __shared__ __align__(16) bf16 As[128 * 32];
    __shared__ __align__(16) bf16 Bs[BN * 32];
    const int tn = blockIdx.x, tm = blockIdx.y;
    const int tid = threadIdx.x;
    const int wave = tid >> 6, lane = tid & 63;
    const int wm = wave >> 1, wn = wave & 1;
    const int quad = lane >> 4, l16 = lane & 15;

    f32x4 acc[4][NT];
#pragma unroll
    for (int i = 0; i < 4; ++i)
#pragma unroll
        for (int j = 0; j < NT; ++j) acc[i][j] = (f32x4){0.f, 0.f, 0.f, 0.f};

    // slot s (16B) <-> (row = s>>2, kseg = (s&3)*8); LDS byte offset = s*16
    const int s_row = tid >> 2, s_seg = (tid & 3) * 8;
    const bf16* Ap = A + (size_t)(tm * 128 + s_row) * K + s_seg;
    const bf16* Bp = Bt + (size_t)(tn * BN + s_row) * K + s_seg;
    const size_t K64 = (size_t)64 * K;
    bf16* lA0 = As + tid * 8;
    bf16* lA1 = As + (256 + tid) * 8;
    bf16* lB0 = Bs + tid * 8;

    const int nk = K / 32;
    for (int kt = 0; kt < nk; ++kt) {
        __syncthreads();
        gld_lds16(Ap, lA0);
        gld_lds16(Ap + K64, lA1);
        gld_lds16(Bp, lB0);
        if constexpr (BN == 128) {
            gld_lds16(Bp + K64, Bs + (256 + tid) * 8);
        }
        __syncthreads();

        bf16x8 aF[4], bF[NT];
#pragma unroll
        for (int mt = 0; mt < 4; ++mt)
            aF[mt] = *(const bf16x8*)(As + (wm * 64 + mt * 16 + l16) * 32 + quad * 8);
#pragma unroll
        for (int nt = 0; nt < NT; ++nt)
            bF[nt] = *(const bf16x8*)(Bs + (wn * (BN / 2) + nt * 16 + l16) * 32 + quad * 8);
#pragma unroll
        for (int mt = 0; mt < 4; ++mt)
#pragma unroll
            for (int nt = 0; nt < NT; ++nt)
                acc[mt][nt] = __builtin_amdgcn_mfma_f32_16x16x32_bf16(
                    aF[mt], bF[nt], acc[mt][nt], 0, 0, 0);

        Ap += 32;
        Bp += 32;
    }

    // epilogue: C/D layout col = lane&15, row = quad*4 + j  [m89/m91-verified]
#pragma unroll
    for (int nt = 0; nt < NT; ++nt) {
        const int col = tn * BN + wn * (BN / 2) + nt * 16 + l16;
        float bv = 0.f;
        if (EPI != 0) bv = bias[col];
#pragma unroll
        for (int mt = 0; mt < 4; ++mt) {
            const int row0 = tm * 128 + wm * 64 + mt * 16 + quad * 4;
#pragma unroll
            for (int j = 0; j < 4; ++j) {
                float v = acc[mt][nt][j];
                const size_t idx = (size_t)(row0 + j) * N + col;
                if (EPI == 1) {
                    v += bv + res[idx];
                    ((float*)Cv)[idx] = v;
                } else if (EPI == 2) {
                    v += bv;
                    v = 0.5f * v * (1.0f + erff(v * 0.70710678118654752f));
                    ((bf16*)Cv)[idx] = f2b(v);
                } else {
                    ((bf16*)Cv)[idx] = f2b(v);
                }
            }
        }
    }
}

// ---------------- MFMA flash attention (causal), pipelined + balanced ----------------
// Grid (16, B*H): block p handles Q-tiles {31-p, p} -> uniform 33 chunks/block.
// K/V double-buffered in LDS; next chunk prefetched (K via global_load_lds, V via
// regs) while current chunk computes -> one barrier per chunk, latency hidden.
__global__ __launch_bounds__(256) void fattn_kernel(const bf16* __restrict__ QKV,
                                                    bf16* __restrict__ ctx) {
    const int pair = blockIdx.x;    // 0..15
    const int bh = blockIdx.y;
    const int b = bh >> 4, h = bh & (H - 1);
    const int tid = threadIdx.x;
    const int wave = tid >> 6, lane = tid & 63;
    const int quad = lane >> 4, l16 = lane & 15;
    const bf16* Qp = QKV + (size_t)b * S * DQ + h * HD;
    const bf16* Kp = Qp + D;
    const bf16* Vp = Qp + 2 * D;

    __shared__ __align__(16) bf16 Ks[2][64 * 64];  // swizzled [key][dseg]
    __shared__ __align__(16) bf16 Vt[2][64][72];   // [d][key]
    __shared__ __align__(16) bf16 Ps[64][72];      // [q][key], wave-private rows

    // K staging slots (2 per thread), XOR-swizzled: slot = key*8 + (dseg ^ (key&7))
    const int keyA = tid >> 3, dsA = ((tid & 7) ^ (keyA & 7)) * 8;
    const int sB = 256 + tid;
    const int keyB = sB >> 3, dsB = ((sB & 7) ^ (keyB & 7)) * 8;

    const int tiles[2] = {S / 64 - 1 - pair, pair};  // big tile first
#pragma unroll
    for (int ti = 0; ti < 2; ++ti) {
        const int t = tiles[ti];
        const int q0 = t * 64;
        // Q fragments (A-layout)
        const bf16* qg = Qp + (size_t)(q0 + wave * 16 + l16) * DQ + quad * 8;
        const bf16x8 aQ0 = *(const bf16x8*)(qg);
        const bf16x8 aQ1 = *(const bf16x8*)(qg + 32);

        f32x4 O[4];
#pragma unroll
        for (int nt = 0; nt < 4; ++nt) O[nt] = (f32x4){0.f, 0.f, 0.f, 0.f};
        float m[4] = {-3.0e38f, -3.0e38f, -3.0e38f, -3.0e38f};
        float l[4] = {0.f, 0.f, 0.f, 0.f};

        // pre-stage chunk 0 into buffer 0
        __syncthreads();  // prior tile's readers done with buf0
        gld_lds16(Kp + (size_t)keyA * DQ + dsA, Ks[0] + tid * 8);
        gld_lds16(Kp + (size_t)keyB * DQ + dsB, Ks[0] + sB * 8);
        {
            const bf16* vg = Vp + (size_t)lane * DQ + wave * 16;
            union { int4 v; bf16 hh[8]; } u0, u1;
            u0.v = *(const int4*)vg;
            u1.v = *(const int4*)(vg + 8);
#pragma unroll
            for (int i = 0; i < 8; ++i) Vt[0][wave * 16 + i][lane] = u0.hh[i];
#pragma unroll
            for (int i = 0; i < 8; ++i) Vt[0][wave * 16 + 8 + i][lane] = u1.hh[i];
        }

        for (int c = 0; c <= t; ++c) {
            const int cur = c & 1, nxt = cur ^ 1;
            __syncthreads();  // buf[cur] ready (drains prefetch vmcnt + V lgkm)
            // prefetch chunk c+1 into buf[nxt]
            union { int4 v; bf16 hh[8]; } u0, u1;
            if (c < t) {
                const int k1 = (c + 1) * 64;
                gld_lds16(Kp + (size_t)(k1 + keyA) * DQ + dsA, Ks[nxt] + tid * 8);
                gld_lds16(Kp + (size_t)(k1 + keyB) * DQ + dsB, Ks[nxt] + sB * 8);
                const bf16* vg = Vp + (size_t)(k1 + lane) * DQ + wave * 16;
                u0.v = *(const int4*)vg;
                u1.v = *(const int4*)(vg + 8);
            }

            // scores: 16q x 64k per wave, scaled by 1/sqrt(64)
            f32x4 sc[4];
#pragma unroll
            for (int nt = 0; nt < 4; ++nt) {
                const int r = nt * 16 + l16;
                const bf16x8 bK0 = *(const bf16x8*)(Ks[cur] + (r * 8 + (quad ^ (r & 7))) * 8);
                const bf16x8 bK1 = *(const bf16x8*)(Ks[cur] + (r * 8 + ((4 + quad) ^ (r & 7))) * 8);
                f32x4 z = (f32x4){0.f, 0.f, 0.f, 0.f};
                z = __builtin_amdgcn_mfma_f32_16x16x32_bf16(aQ0, bK0, z, 0, 0, 0);
                z = __builtin_amdgcn_mfma_f32_16x16x32_bf16(aQ1, bK1, z, 0, 0, 0);
                sc[nt] = z;
            }
#pragma unroll
            for (int nt = 0; nt < 4; ++nt)
#pragma unroll
                for (int j = 0; j < 4; ++j) sc[nt][j] *= 0.125f;
            // causal mask — only the diagonal chunk
            if (c == t) {
#pragma unroll
                for (int nt = 0; nt < 4; ++nt) {
                    const int key_l = nt * 16 + l16;
#pragma unroll
                    for (int j = 0; j < 4; ++j)
                        if (key_l > wave * 16 + quad * 4 + j) sc[nt][j] = -3.0e38f;
                }
            }
            // online softmax (rows = quad*4+j; reduce across 16 lanes)
            float al[4];
#pragma unroll
            for (int j = 0; j < 4; ++j) {
                float mx = fmaxf(fmaxf(sc[0][j], sc[1][j]), fmaxf(sc[2][j], sc[3][j]));
#pragma unroll
                for (int off = 1; off <= 8; off <<= 1) mx = fmaxf(mx, __shfl_xor(mx, off));
                const float mn = fmaxf(m[j], mx);
                al[j] = __expf(m[j] - mn);
                m[j] = mn;
                float rs = 0.f;
#pragma unroll
                for (int nt = 0; nt < 4; ++nt) {
                    sc[nt][j] = __expf(sc[nt][j] - mn);
                    rs += sc[nt][j];
                }
#pragma unroll
                for (int off = 1; off <= 8; off <<= 1) rs += __shfl_xor(rs, off);
                l[j] = l[j] * al[j] + rs;
            }
            // P: C-layout -> LDS -> A-layout (wave-private rows)
#pragma unroll
            for (int nt = 0; nt < 4; ++nt)
#pragma unroll
                for (int j = 0; j < 4; ++j)
                    Ps[wave * 16 + quad * 4 + j][nt * 16 + l16] = f2b(sc[nt][j]);
            asm volatile("s_waitcnt lgkmcnt(0)" ::: "memory");
            const bf16x8 aP0 = *(const bf16x8*)&Ps[wave * 16 + l16][quad * 8];
            const bf16x8 aP1 = *(const bf16x8*)&Ps[wave * 16 + l16][32 + quad * 8];
            // O = O*alpha + P V
#pragma unroll
            for (int nt = 0; nt < 4; ++nt)
#pragma unroll
                for (int j = 0; j < 4; ++j) O[nt][j] *= al[j];
#pragma unroll
            for (int nt = 0; nt < 4; ++nt) {
                const bf16x8 bV0 = *(const bf16x8*)&Vt[cur][nt * 16 + l16][quad * 8];
                const bf16x8 bV1 = *(const bf16x8*)&Vt[cur][nt * 16 + l16][32 + quad * 8];
                O[nt] = __builtin_amdgcn_mfma_f32_16x16x32_bf16(aP0, bV0, O[nt], 0, 0, 0);
                O[nt] = __builtin_amdgcn_mfma_f32_16x16x32_bf16(aP1, bV1, O[nt], 0, 0, 0);
            }
            // commit prefetched V into buf[nxt]
            if (c < t) {
#pragma unroll
                for (int i = 0; i < 8; ++i) Vt[nxt][wave * 16 + i][lane] = u0.hh[i];
#pragma unroll
                for (int i = 0; i < 8; ++i) Vt[nxt][wave * 16 + 8 + i][lane] = u1.hh[i];
            }
        }

        // finalize: ctx compact [token][h*64+d], stride D
        const size_t hoC = (size_t)b * S * D + h * HD;
        float rl[4];
#pragma unroll
        for (int j = 0; j < 4; ++j) rl[j] = 1.0f / l[j];
#pragma unroll
        for (int nt = 0; nt < 4; ++nt)
#pragma unroll
            for (int j = 0; j < 4; ++j)
                ctx[hoC + (size_t)(q0 + wave * 16 + quad * 4 + j) * D + nt * 16 + l16] =
                    f2b(O[nt][j] * rl[j]);
    }
}

// ---------------- launcher ----------------
extern "C" void kernel_launch(void* const* d_in, const int* in_sizes, int n_in,
                              void* d_out, int out_size, void* d_ws, size_t ws_size,
                              hipStream_t stream) {
    const float* x     = (const float*)d_in[0];
    const float* ln1_g = (const float*)d_in[1];
    const float* ln1_b = (const float*)d_in[2];
    const float* Wq    = (const float*)d_in[3];
    const float* Wk    = (const float*)d_in[4];
    const float* Wv    = (const float*)d_in[5];
    const float* Wo    = (const float*)d_in[6];
    const float* bo    = (const float*)d_in[7];
    const float* ln2_g = (const float*)d_in[8];
    const float* ln2_b = (const float*)d_in[9];
    const float* W1    = (const float*)d_in[10];
    const float* b1    = (const float*)d_in[11];
    const float* W2    = (const float*)d_in[12];
    const float* b2    = (const float*)d_in[13];
    float* out = (float*)d_out;

    // workspace (MB), lifetime-overlapped; peak 64 MB:
    //   [ 0, 8): h (LN1 out)            -> W1T (conv after QKV gemm)
    //   [ 8,32): QKVb (packed, 24 MB)   \
    //   [32,40): ctx (attn out)          } -> hff [8,40) (32 MB)
    //   [40,48): h2 (LN2 out)
    //   [48,54): WqkvT   [54,56): WoT   [56,64): W2T
    //   x2 (fp32 residual) lives in d_out; final GEMM reads it in-place.
    char* ws = (char*)d_ws;
    const size_t MB = (size_t)1 << 20;
    bf16* h     = (bf16*)(ws + 0 * MB);
    bf16* W1T   = (bf16*)(ws + 0 * MB);
    bf16* QKVb  = (bf16*)(ws + 8 * MB);
    bf16* hff   = (bf16*)(ws + 8 * MB);
    bf16* ctx   = (bf16*)(ws + 32 * MB);
    bf16* h2    = (bf16*)(ws + 40 * MB);
    bf16* WqkvT = (bf16*)(ws + 48 * MB);
    bf16* WoT   = (bf16*)(ws + 54 * MB);
    bf16* W2T   = (bf16*)(ws + 56 * MB);

    // --- 0) transpose-convert weights (Wq/Wk/Wv fused into one B^T) ---
    dim3 gt(16, 16);
    convT_kernel<<<gt, 256, 0, stream>>>(Wq, WqkvT,                 D, D);
    convT_kernel<<<gt, 256, 0, stream>>>(Wk, WqkvT + (size_t)D * D, D, D);
    convT_kernel<<<gt, 256, 0, stream>>>(Wv, WqkvT + (size_t)2 * D * D, D, D);
    convT_kernel<<<gt, 256, 0, stream>>>(Wo, WoT, D, D);
    convT_kernel<<<dim3(64, 16), 256, 0, stream>>>(W2, W2T, DFF, D);
    // --- 1) LN1 ---
    ln_kernel<<<NR, 256, 0, stream>>>(x, ln1_g, ln1_b, h);
    // --- 2) QKV = h @ [Wq|Wk|Wv]   [4096,1024]x[1024,3072] ---
    gemm_bt<0, 128><<<dim3(DQ / 128, NR / 128), 256, 0, stream>>>(
        h, WqkvT, nullptr, nullptr, QKVb, NR, DQ, D);
    // h dead now -> W1T into [0,8)
    convT_kernel<<<dim3(16, 64), 256, 0, stream>>>(W1, W1T, D, DFF);
    // --- 3) flash attention -> ctx ---
    fattn_kernel<<<dim3(S / 128, B * H), 256, 0, stream>>>(QKVb, ctx);
    // --- 4) x2 = x + ctx @ Wo + bo   (fp32 into d_out) ---
    gemm_bt<1, 64><<<dim3(D / 64, NR / 128), 256, 0, stream>>>(
        ctx, WoT, bo, x, out, NR, D, D);
    // --- 5) LN2 ---
    ln_kernel<<<NR, 256, 0, stream>>>(out, ln2_g, ln2_b, h2);
    // --- 6) hff = gelu(h2 @ W1 + b1)   [4096,1024]x[1024,4096] ---
    gemm_bt<2, 128><<<dim3(DFF / 128, NR / 128), 256, 0, stream>>>(
        h2, W1T, b1, nullptr, hff, NR, DFF, D);
    // --- 7) out = x2 + hff @ W2 + b2   [4096,4096]x[4096,1024], in-place ---
    gemm_bt<1, 64><<<dim3(D / 64, NR / 128), 256, 0, stream>>>(
        hff, W2T, b2, out, out, NR, D, DFF);
}

// Round 7
// 437.494 us; speedup vs baseline: 12.0450x; 1.0033x over previous
//
#include <hip/hip_runtime.h>
#include <hip/hip_bf16.h>
#include <math.h>

using bf16 = __hip_bfloat16;
typedef short bf16x8 __attribute__((ext_vector_type(8)));
typedef float f32x4 __attribute__((ext_vector_type(4)));

static constexpr int B = 2, S = 2048, D = 1024, H = 16, HD = 64, DFF = 4096;
static constexpr int NR = B * S;   // 4096 rows
static constexpr int DQ = 3072;    // packed QKV row stride
static constexpr float EPS = 1e-5f;

__device__ __forceinline__ bf16 f2b(float v) { return __float2bfloat16(v); }

// async global->LDS, 16B per lane; LDS dest must be wave-uniform base + lane*16
typedef __attribute__((address_space(1))) const void* gp1_t;
typedef __attribute__((address_space(3))) void* sp3_t;
__device__ __forceinline__ void gld_lds16(const bf16* g, bf16* l) {
    __builtin_amdgcn_global_load_lds((gp1_t)(const void*)g, (sp3_t)(void*)l, 16, 0, 0);
}

// ---------------- tiled transpose + fp32->bf16: dst[n][k] = src[k][n] ----------------
__global__ __launch_bounds__(256) void convT_kernel(const float* __restrict__ src, // [K][N]
                                                    bf16* __restrict__ dst,        // [N][K]
                                                    int K, int N) {
    __shared__ float tile[64][65];
    const int k0 = blockIdx.x * 64, n0 = blockIdx.y * 64;
    const int tid = threadIdx.x;
    const int r = tid >> 4, c = (tid & 15) * 4;
#pragma unroll
    for (int rr = 0; rr < 64; rr += 16) {
        float4 v = *(const float4*)&src[(size_t)(k0 + r + rr) * N + n0 + c];
        tile[r + rr][c] = v.x; tile[r + rr][c + 1] = v.y;
        tile[r + rr][c + 2] = v.z; tile[r + rr][c + 3] = v.w;
    }
    __syncthreads();
    const int n = tid >> 2, ks = (tid & 3) * 16;
    union { bf16 h[16]; int4 v2[2]; } o;
#pragma unroll
    for (int i = 0; i < 16; ++i) o.h[i] = f2b(tile[ks + i][n]);
    bf16* dp = &dst[(size_t)(n0 + n) * K + k0 + ks];
    *(int4*)dp = o.v2[0];
    *(int4*)(dp + 8) = o.v2[1];
}

// ---------------- LayerNorm: fp32 in, bf16 out; one block per row ----------------
__global__ __launch_bounds__(256) void ln_kernel(const float* __restrict__ x,
                                                 const float* __restrict__ g,
                                                 const float* __restrict__ b,
                                                 bf16* __restrict__ out) {
    const int row = blockIdx.x;
    const int tid = threadIdx.x;
    const float4 v4 = ((const float4*)(x + (size_t)row * D))[tid];
    float v[4] = {v4.x, v4.y, v4.z, v4.w};
    float s = v[0] + v[1] + v[2] + v[3];
    float sq = v[0] * v[0] + v[1] * v[1] + v[2] * v[2] + v[3] * v[3];
#pragma unroll
    for (int off = 32; off >= 1; off >>= 1) {
        s += __shfl_xor(s, off);
        sq += __shfl_xor(sq, off);
    }
    __shared__ float ssum[4], ssq[4];
    const int wave = tid >> 6;
    if ((tid & 63) == 0) { ssum[wave] = s; ssq[wave] = sq; }
    __syncthreads();
    s = ssum[0] + ssum[1] + ssum[2] + ssum[3];
    sq = ssq[0] + ssq[1] + ssq[2] + ssq[3];
    const float mu = s * (1.0f / D);
    const float var = sq * (1.0f / D) - mu * mu;
    const float rstd = rsqrtf(var + EPS);
    bf16* orow = out + (size_t)row * D;
#pragma unroll
    for (int i = 0; i < 4; ++i) {
        const int c = tid * 4 + i;
        orow[c] = f2b((v[i] - mu) * rstd * g[c] + b[c]);
    }
}

// ---------------- GEMM (m97 structure): C[M,N] = A[M,K] @ Bt[N,K]^T ----------------
// Grid: blockIdx.x = n-tile (consecutive blocks share the A strip -> L2 reuse),
// blockIdx.y = m-tile. 128 x BN tile, 4 waves 2x2, global_load_lds staging.
// EPI 0: bf16 out. EPI 1: + fp32 bias + fp32 residual, fp32 out (res==C OK).
// EPI 2: + fp32 bias + exact GELU, bf16 out.
template <int EPI, int BN>
__global__ __launch_bounds__(256) void gemm_bt(const bf16* __restrict__ A,
                                               const bf16* __restrict__ Bt,
                                               const float* __restrict__ bias,
                                               const float* __restrict__ res,
                                               void* __restrict__ Cv,
                                               int M, int N, int K) {
    constexpr int NT = BN / 32;               // n-tiles per wave
    __shared__ __align__(16) bf16 As[128 * 32];
    __shared__ __align__(16) bf16 Bs[BN * 32];
    const int tn = blockIdx.x, tm = blockIdx.y;
    const int tid = threadIdx.x;
    const int wave = tid >> 6, lane = tid & 63;
    const int wm = wave >> 1, wn = wave & 1;
    const int quad = lane >> 4, l16 = lane & 15;

    f32x4 acc[4][NT];
#pragma unroll
    for (int i = 0; i < 4; ++i)
#pragma unroll
        for (int j = 0; j < NT; ++j) acc[i][j] = (f32x4){0.f, 0.f, 0.f, 0.f};

    // slot s (16B) <-> (row = s>>2, kseg = (s&3)*8); LDS byte offset = s*16
    const int s_row = tid >> 2, s_seg = (tid & 3) * 8;
    const bf16* Ap = A + (size_t)(tm * 128 + s_row) * K + s_seg;
    const bf16* Bp = Bt + (size_t)(tn * BN + s_row) * K + s_seg;
    const size_t K64 = (size_t)64 * K;
    bf16* lA0 = As + tid * 8;
    bf16* lA1 = As + (256 + tid) * 8;
    bf16* lB0 = Bs + tid * 8;

    const int nk = K / 32;
    for (int kt = 0; kt < nk; ++kt) {
        __syncthreads();
        gld_lds16(Ap, lA0);
        gld_lds16(Ap + K64, lA1);
        gld_lds16(Bp, lB0);
        if constexpr (BN == 128) {
            gld_lds16(Bp + K64, Bs + (256 + tid) * 8);
        }
        __syncthreads();

        bf16x8 aF[4], bF[NT];
#pragma unroll
        for (int mt = 0; mt < 4; ++mt)
            aF[mt] = *(const bf16x8*)(As + (wm * 64 + mt * 16 + l16) * 32 + quad * 8);
#pragma unroll
        for (int nt = 0; nt < NT; ++nt)
            bF[nt] = *(const bf16x8*)(Bs + (wn * (BN / 2) + nt * 16 + l16) * 32 + quad * 8);
#pragma unroll
        for (int mt = 0; mt < 4; ++mt)
#pragma unroll
            for (int nt = 0; nt < NT; ++nt)
                acc[mt][nt] = __builtin_amdgcn_mfma_f32_16x16x32_bf16(
                    aF[mt], bF[nt], acc[mt][nt], 0, 0, 0);

        Ap += 32;
        Bp += 32;
    }

    // epilogue: C/D layout col = lane&15, row = quad*4 + j  [m89/m91-verified]
#pragma unroll
    for (int nt = 0; nt < NT; ++nt) {
        const int col = tn * BN + wn * (BN / 2) + nt * 16 + l16;
        float bv = 0.f;
        if (EPI != 0) bv = bias[col];
#pragma unroll
        for (int mt = 0; mt < 4; ++mt) {
            const int row0 = tm * 128 + wm * 64 + mt * 16 + quad * 4;
#pragma unroll
            for (int j = 0; j < 4; ++j) {
                float v = acc[mt][nt][j];
                const size_t idx = (size_t)(row0 + j) * N + col;
                if (EPI == 1) {
                    v += bv + res[idx];
                    ((float*)Cv)[idx] = v;
                } else if (EPI == 2) {
                    v += bv;
                    v = 0.5f * v * (1.0f + erff(v * 0.70710678118654752f));
                    ((bf16*)Cv)[idx] = f2b(v);
                } else {
                    ((bf16*)Cv)[idx] = f2b(v);
                }
            }
        }
    }
}

// ---------------- MFMA flash attention (causal), XCD-local + 128-query tiles ----------
// Grid 256 (1-D): id = pair*32 + bh -> id%8 = bh%8, so all 8 blocks of a head land on
// one XCD (4 heads/XCD = 2 MB K/V working set, L2-resident). Block: 512 threads,
// 8 waves x 16 q-rows = 128 queries; pair p handles tiles {15-p, p} = uniform 34
// chunks of 64 keys. K/V double-buffered, distance-1 prefetch (K via global_load_lds,
// V via regs), one barrier per chunk.
__global__ __launch_bounds__(512) void fattn_kernel(const bf16* __restrict__ QKV,
                                                    bf16* __restrict__ ctx) {
    const int id = blockIdx.x;
    const int pair = id >> 5;       // 0..7
    const int bh = id & 31;
    const int b = bh >> 4, h = bh & (H - 1);
    const int tid = threadIdx.x;
    const int wave = tid >> 6, lane = tid & 63;
    const int quad = lane >> 4, l16 = lane & 15;
    const bf16* Qp = QKV + (size_t)b * S * DQ + h * HD;
    const bf16* Kp = Qp + D;
    const bf16* Vp = Qp + 2 * D;

    __shared__ __align__(16) bf16 Ks[2][64 * 64];  // swizzled [key][dseg]
    __shared__ __align__(16) bf16 Vt[2][64][72];   // [d][key]
    __shared__ __align__(16) bf16 Ps[128][76];     // [q][key], wave-private rows; +76 stride

    // K staging: 1 slot (16B) per thread; slot = key*8 + (dseg ^ (key&7))
    const int keyA = tid >> 3, dsA = ((tid & 7) ^ (keyA & 7)) * 8;

    const int tiles[2] = {S / 128 - 1 - pair, pair};  // big tile first
#pragma unroll
    for (int ti = 0; ti < 2; ++ti) {
        const int t = tiles[ti];
        const int q0 = t * 128;
        // Q fragments (A-layout); wave w owns q-rows [w*16, w*16+16)
        const bf16* qg = Qp + (size_t)(q0 + wave * 16 + l16) * DQ + quad * 8;
        const bf16x8 aQ0 = *(const bf16x8*)(qg);
        const bf16x8 aQ1 = *(const bf16x8*)(qg + 32);

        f32x4 O[4];
#pragma unroll
        for (int nt = 0; nt < 4; ++nt) O[nt] = (f32x4){0.f, 0.f, 0.f, 0.f};
        float m[4] = {-3.0e38f, -3.0e38f, -3.0e38f, -3.0e38f};
        float l[4] = {0.f, 0.f, 0.f, 0.f};

        // pre-stage chunk 0 into buffer 0 (prev tile's last chunk used buf1: nch even)
        __syncthreads();
        gld_lds16(Kp + (size_t)keyA * DQ + dsA, Ks[0] + tid * 8);
        {
            // V: wave w stages d in [w*8, w*8+8), key = lane
            const bf16* vg = Vp + (size_t)lane * DQ + wave * 8;
            union { int4 v; bf16 hh[8]; } u;
            u.v = *(const int4*)vg;
#pragma unroll
            for (int i = 0; i < 8; ++i) Vt[0][wave * 8 + i][lane] = u.hh[i];
        }

        const int nch = 2 * t + 2;
        for (int c = 0; c < nch; ++c) {
            const int cur = c & 1, nxt = cur ^ 1;
            __syncthreads();  // buf[cur] ready (drains prefetch vmcnt + V lgkm)
            // prefetch chunk c+1 into buf[nxt]
            union { int4 v; bf16 hh[8]; } u;
            if (c < nch - 1) {
                const int k1 = (c + 1) * 64;
                gld_lds16(Kp + (size_t)(k1 + keyA) * DQ + dsA, Ks[nxt] + tid * 8);
                u.v = *(const int4*)(Vp + (size_t)(k1 + lane) * DQ + wave * 8);
            }

            // scores: 16q x 64k per wave, scaled by 1/sqrt(64)
            f32x4 sc[4];
#pragma unroll
            for (int nt = 0; nt < 4; ++nt) {
                const int r = nt * 16 + l16;
                const bf16x8 bK0 = *(const bf16x8*)(Ks[cur] + (r * 8 + (quad ^ (r & 7))) * 8);
                const bf16x8 bK1 = *(const bf16x8*)(Ks[cur] + (r * 8 + ((4 + quad) ^ (r & 7))) * 8);
                f32x4 z = (f32x4){0.f, 0.f, 0.f, 0.f};
                z = __builtin_amdgcn_mfma_f32_16x16x32_bf16(aQ0, bK0, z, 0, 0, 0);
                z = __builtin_amdgcn_mfma_f32_16x16x32_bf16(aQ1, bK1, z, 0, 0, 0);
                sc[nt] = z;
            }
#pragma unroll
            for (int nt = 0; nt < 4; ++nt)
#pragma unroll
                for (int j = 0; j < 4; ++j) sc[nt][j] *= 0.125f;
            // causal mask — last two chunks intersect the 128-row diagonal band
            if (c >= 2 * t) {
                const int kbase = (c - 2 * t) * 64;
#pragma unroll
                for (int nt = 0; nt < 4; ++nt) {
                    const int rel_k = kbase + nt * 16 + l16;
#pragma unroll
                    for (int j = 0; j < 4; ++j)
                        if (rel_k > wave * 16 + quad * 4 + j) sc[nt][j] = -3.0e38f;
                }
            }
            // online softmax (rows = quad*4+j; reduce across 16 lanes)
            float al[4];
#pragma unroll
            for (int j = 0; j < 4; ++j) {
                float mx = fmaxf(fmaxf(sc[0][j], sc[1][j]), fmaxf(sc[2][j], sc[3][j]));
#pragma unroll
                for (int off = 1; off <= 8; off <<= 1) mx = fmaxf(mx, __shfl_xor(mx, off));
                const float mn = fmaxf(m[j], mx);
                al[j] = __expf(m[j] - mn);
                m[j] = mn;
                float rs = 0.f;
#pragma unroll
                for (int nt = 0; nt < 4; ++nt) {
                    sc[nt][j] = __expf(sc[nt][j] - mn);
                    rs += sc[nt][j];
                }
#pragma unroll
                for (int off = 1; off <= 8; off <<= 1) rs += __shfl_xor(rs, off);
                l[j] = l[j] * al[j] + rs;
            }
            // P: C-layout -> LDS -> A-layout (wave-private rows)
#pragma unroll
            for (int nt = 0; nt < 4; ++nt)
#pragma unroll
                for (int j = 0; j < 4; ++j)
                    Ps[wave * 16 + quad * 4 + j][nt * 16 + l16] = f2b(sc[nt][j]);
            asm volatile("s_waitcnt lgkmcnt(0)" ::: "memory");
            const bf16x8 aP0 = *(const bf16x8*)&Ps[wave * 16 + l16][quad * 8];
            const bf16x8 aP1 = *(const bf16x8*)&Ps[wave * 16 + l16][32 + quad * 8];
            // O = O*alpha + P V
#pragma unroll
            for (int nt = 0; nt < 4; ++nt)
#pragma unroll
                for (int j = 0; j < 4; ++j) O[nt][j] *= al[j];
#pragma unroll
            for (int nt = 0; nt < 4; ++nt) {
                const bf16x8 bV0 = *(const bf16x8*)&Vt[cur][nt * 16 + l16][quad * 8];
                const bf16x8 bV1 = *(const bf16x8*)&Vt[cur][nt * 16 + l16][32 + quad * 8];
                O[nt] = __builtin_amdgcn_mfma_f32_16x16x32_bf16(aP0, bV0, O[nt], 0, 0, 0);
                O[nt] = __builtin_amdgcn_mfma_f32_16x16x32_bf16(aP1, bV1, O[nt], 0, 0, 0);
            }
            // commit prefetched V into buf[nxt]
            if (c < nch - 1) {
#pragma unroll
                for (int i = 0; i < 8; ++i) Vt[nxt][wave * 8 + i][lane] = u.hh[i];
            }
        }

        // finalize: ctx compact [token][h*64+d], stride D
        const size_t hoC = (size_t)b * S * D + h * HD;
        float rl[4];
#pragma unroll
        for (int j = 0; j < 4; ++j) rl[j] = 1.0f / l[j];
#pragma unroll
        for (int nt = 0; nt < 4; ++nt)
#pragma unroll
            for (int j = 0; j < 4; ++j)
                ctx[hoC + (size_t)(q0 + wave * 16 + quad * 4 + j) * D + nt * 16 + l16] =
                    f2b(O[nt][j] * rl[j]);
    }
}

// ---------------- launcher ----------------
extern "C" void kernel_launch(void* const* d_in, const int* in_sizes, int n_in,
                              void* d_out, int out_size, void* d_ws, size_t ws_size,
                              hipStream_t stream) {
    const float* x     = (const float*)d_in[0];
    const float* ln1_g = (const float*)d_in[1];
    const float* ln1_b = (const float*)d_in[2];
    const float* Wq    = (const float*)d_in[3];
    const float* Wk    = (const float*)d_in[4];
    const float* Wv    = (const float*)d_in[5];
    const float* Wo    = (const float*)d_in[6];
    const float* bo    = (const float*)d_in[7];
    const float* ln2_g = (const float*)d_in[8];
    const float* ln2_b = (const float*)d_in[9];
    const float* W1    = (const float*)d_in[10];
    const float* b1    = (const float*)d_in[11];
    const float* W2    = (const float*)d_in[12];
    const float* b2    = (const float*)d_in[13];
    float* out = (float*)d_out;

    // workspace (MB), lifetime-overlapped; peak 64 MB:
    //   [ 0, 8): h (LN1 out)            -> W1T (conv after QKV gemm)
    //   [ 8,32): QKVb (packed, 24 MB)   \
    //   [32,40): ctx (attn out)          } -> hff [8,40) (32 MB)
    //   [40,48): h2 (LN2 out)
    //   [48,54): WqkvT   [54,56): WoT   [56,64): W2T
    //   x2 (fp32 residual) lives in d_out; final GEMM reads it in-place.
    char* ws = (char*)d_ws;
    const size_t MB = (size_t)1 << 20;
    bf16* h     = (bf16*)(ws + 0 * MB);
    bf16* W1T   = (bf16*)(ws + 0 * MB);
    bf16* QKVb  = (bf16*)(ws + 8 * MB);
    bf16* hff   = (bf16*)(ws + 8 * MB);
    bf16* ctx   = (bf16*)(ws + 32 * MB);
    bf16* h2    = (bf16*)(ws + 40 * MB);
    bf16* WqkvT = (bf16*)(ws + 48 * MB);
    bf16* WoT   = (bf16*)(ws + 54 * MB);
    bf16* W2T   = (bf16*)(ws + 56 * MB);

    // --- 0) transpose-convert weights (Wq/Wk/Wv fused into one B^T) ---
    dim3 gt(16, 16);
    convT_kernel<<<gt, 256, 0, stream>>>(Wq, WqkvT,                 D, D);
    convT_kernel<<<gt, 256, 0, stream>>>(Wk, WqkvT + (size_t)D * D, D, D);
    convT_kernel<<<gt, 256, 0, stream>>>(Wv, WqkvT + (size_t)2 * D * D, D, D);
    convT_kernel<<<gt, 256, 0, stream>>>(Wo, WoT, D, D);
    convT_kernel<<<dim3(64, 16), 256, 0, stream>>>(W2, W2T, DFF, D);
    // --- 1) LN1 ---
    ln_kernel<<<NR, 256, 0, stream>>>(x, ln1_g, ln1_b, h);
    // --- 2) QKV = h @ [Wq|Wk|Wv]   [4096,1024]x[1024,3072] ---
    gemm_bt<0, 128><<<dim3(DQ / 128, NR / 128), 256, 0, stream>>>(
        h, WqkvT, nullptr, nullptr, QKVb, NR, DQ, D);
    // h dead now -> W1T into [0,8)
    convT_kernel<<<dim3(16, 64), 256, 0, stream>>>(W1, W1T, D, DFF);
    // --- 3) flash attention -> ctx ---
    fattn_kernel<<<dim3((S / 128 / 2) * B * H), 512, 0, stream>>>(QKVb, ctx);
    // --- 4) x2 = x + ctx @ Wo + bo   (fp32 into d_out) ---
    gemm_bt<1, 64><<<dim3(D / 64, NR / 128), 256, 0, stream>>>(
        ctx, WoT, bo, x, out, NR, D, D);
    // --- 5) LN2 ---
    ln_kernel<<<NR, 256, 0, stream>>>(out, ln2_g, ln2_b, h2);
    // --- 6) hff = gelu(h2 @ W1 + b1)   [4096,1024]x[1024,4096] ---
    gemm_bt<2, 128><<<dim3(DFF / 128, NR / 128), 256, 0, stream>>>(
        h2, W1T, b1, nullptr, hff, NR, DFF, D);
    // --- 7) out = x2 + hff @ W2 + b2   [4096,4096]x[4096,1024], in-place ---
    gemm_bt<1, 64><<<dim3(D / 64, NR / 128), 256, 0, stream>>>(
        hff, W2T, b2, out, out, NR, D, DFF);
}

// Round 8
// 419.565 us; speedup vs baseline: 12.5597x; 1.0427x over previous
//
#include <hip/hip_runtime.h>
#include <hip/hip_bf16.h>
#include <math.h>

using bf16 = __hip_bfloat16;
typedef short bf16x8 __attribute__((ext_vector_type(8)));
typedef float f32x4 __attribute__((ext_vector_type(4)));

static constexpr int B = 2, S = 2048, D = 1024, H = 16, HD = 64, DFF = 4096;
static constexpr int NR = B * S;   // 4096 rows
static constexpr int DQ = 3072;    // packed QKV row stride
static constexpr float EPS = 1e-5f;

__device__ __forceinline__ bf16 f2b(float v) { return __float2bfloat16(v); }

// async global->LDS, 16B per lane; LDS dest must be wave-uniform base + lane*16
typedef __attribute__((address_space(1))) const void* gp1_t;
typedef __attribute__((address_space(3))) void* sp3_t;
__device__ __forceinline__ void gld_lds16(const bf16* g, bf16* l) {
    __builtin_amdgcn_global_load_lds((gp1_t)(const void*)g, (sp3_t)(void*)l, 16, 0, 0);
}

// ---------------- tiled transpose + fp32->bf16: dst[n][k] = src[k][n] ----------------
__global__ __launch_bounds__(256) void convT_kernel(const float* __restrict__ src, // [K][N]
                                                    bf16* __restrict__ dst,        // [N][K]
                                                    int K, int N) {
    __shared__ float tile[64][65];
    const int k0 = blockIdx.x * 64, n0 = blockIdx.y * 64;
    const int tid = threadIdx.x;
    const int r = tid >> 4, c = (tid & 15) * 4;
#pragma unroll
    for (int rr = 0; rr < 64; rr += 16) {
        float4 v = *(const float4*)&src[(size_t)(k0 + r + rr) * N + n0 + c];
        tile[r + rr][c] = v.x; tile[r + rr][c + 1] = v.y;
        tile[r + rr][c + 2] = v.z; tile[r + rr][c + 3] = v.w;
    }
    __syncthreads();
    const int n = tid >> 2, ks = (tid & 3) * 16;
    union { bf16 h[16]; int4 v2[2]; } o;
#pragma unroll
    for (int i = 0; i < 16; ++i) o.h[i] = f2b(tile[ks + i][n]);
    bf16* dp = &dst[(size_t)(n0 + n) * K + k0 + ks];
    *(int4*)dp = o.v2[0];
    *(int4*)(dp + 8) = o.v2[1];
}

// ---------------- LayerNorm: fp32 in, bf16 out; one block per row ----------------
__global__ __launch_bounds__(256) void ln_kernel(const float* __restrict__ x,
                                                 const float* __restrict__ g,
                                                 const float* __restrict__ b,
                                                 bf16* __restrict__ out) {
    const int row = blockIdx.x;
    const int tid = threadIdx.x;
    const float4 v4 = ((const float4*)(x + (size_t)row * D))[tid];
    float v[4] = {v4.x, v4.y, v4.z, v4.w};
    float s = v[0] + v[1] + v[2] + v[3];
    float sq = v[0] * v[0] + v[1] * v[1] + v[2] * v[2] + v[3] * v[3];
#pragma unroll
    for (int off = 32; off >= 1; off >>= 1) {
        s += __shfl_xor(s, off);
        sq += __shfl_xor(sq, off);
    }
    __shared__ float ssum[4], ssq[4];
    const int wave = tid >> 6;
    if ((tid & 63) == 0) { ssum[wave] = s; ssq[wave] = sq; }
    __syncthreads();
    s = ssum[0] + ssum[1] + ssum[2] + ssum[3];
    sq = ssq[0] + ssq[1] + ssq[2] + ssq[3];
    const float mu = s * (1.0f / D);
    const float var = sq * (1.0f / D) - mu * mu;
    const float rstd = rsqrtf(var + EPS);
    bf16* orow = out + (size_t)row * D;
#pragma unroll
    for (int i = 0; i < 4; ++i) {
        const int c = tid * 4 + i;
        orow[c] = f2b((v[i] - mu) * rstd * g[c] + b[c]);
    }
}

// ---------------- GEMM: C[M,N] = A[M,K] @ Bt[N,K]^T, dbuf + XCD-local grid --------
// 1-D grid, NB = (M/128)*(N/BN); id -> tm = (id/(8*NT))*8 + id%8, tn = (id%(8*NT))/8.
// Blocks with id%8 == x (one XCD under round-robin dispatch) share an A m-strip ->
// A L2-resident per XCD. K-loop: LDS double-buffer, distance-1 prefetch across the
// barrier (global_load_lds issued after barrier, drained by the NEXT barrier ->
// one full compute period of latency slack).
// EPI 0: bf16 out. EPI 1: + fp32 bias + fp32 residual, fp32 out (res==C OK).
// EPI 2: + fp32 bias + exact GELU, bf16 out.
template <int EPI, int BN>
__global__ __launch_bounds__(256) void gemm_bt(const bf16* __restrict__ A,
                                               const bf16* __restrict__ Bt,
                                               const float* __restrict__ bias,
                                               const float* __restrict__ res,
                                               void* __restrict__ Cv,
                                               int M, int N, int K) {
    constexpr int NTW = BN / 32;              // n-tiles per wave
    __shared__ __align__(16) bf16 As[2][128 * 32];
    __shared__ __align__(16) bf16 Bs[2][BN * 32];
    const int NT = N / BN;
    const int id = blockIdx.x;
    const int local = id % (8 * NT);
    const int tm = (id / (8 * NT)) * 8 + (local & 7);
    const int tn = local >> 3;
    const int tid = threadIdx.x;
    const int wave = tid >> 6, lane = tid & 63;
    const int wm = wave >> 1, wn = wave & 1;
    const int quad = lane >> 4, l16 = lane & 15;

    f32x4 acc[4][NTW];
#pragma unroll
    for (int i = 0; i < 4; ++i)
#pragma unroll
        for (int j = 0; j < NTW; ++j) acc[i][j] = (f32x4){0.f, 0.f, 0.f, 0.f};

    // slot s (16B) <-> (row = s>>2, kseg = (s&3)*8)
    const int s_row = tid >> 2, s_seg = (tid & 3) * 8;
    const bf16* Ap = A + (size_t)(tm * 128 + s_row) * K + s_seg;
    const bf16* Bp = Bt + (size_t)(tn * BN + s_row) * K + s_seg;
    const size_t K64 = (size_t)64 * K;

    // prologue: stage slab 0 into buf 0
    gld_lds16(Ap, As[0] + tid * 8);
    gld_lds16(Ap + K64, As[0] + (256 + tid) * 8);
    gld_lds16(Bp, Bs[0] + tid * 8);
    if constexpr (BN == 128) gld_lds16(Bp + K64, Bs[0] + (256 + tid) * 8);
    Ap += 32;
    Bp += 32;

    const int nk = K / 32;
    for (int kt = 0; kt < nk; ++kt) {
        const int cur = kt & 1, nxt = cur ^ 1;
        __syncthreads();  // drains prefetch issued one full iteration ago
        if (kt + 1 < nk) {
            gld_lds16(Ap, As[nxt] + tid * 8);
            gld_lds16(Ap + K64, As[nxt] + (256 + tid) * 8);
            gld_lds16(Bp, Bs[nxt] + tid * 8);
            if constexpr (BN == 128) gld_lds16(Bp + K64, Bs[nxt] + (256 + tid) * 8);
            Ap += 32;
            Bp += 32;
        }

        bf16x8 aF[4], bF[NTW];
#pragma unroll
        for (int mt = 0; mt < 4; ++mt)
            aF[mt] = *(const bf16x8*)(As[cur] + (wm * 64 + mt * 16 + l16) * 32 + quad * 8);
#pragma unroll
        for (int nt = 0; nt < NTW; ++nt)
            bF[nt] = *(const bf16x8*)(Bs[cur] + (wn * (BN / 2) + nt * 16 + l16) * 32 + quad * 8);
#pragma unroll
        for (int mt = 0; mt < 4; ++mt)
#pragma unroll
            for (int nt = 0; nt < NTW; ++nt)
                acc[mt][nt] = __builtin_amdgcn_mfma_f32_16x16x32_bf16(
                    aF[mt], bF[nt], acc[mt][nt], 0, 0, 0);
    }

    // epilogue: C/D layout col = lane&15, row = quad*4 + j  [m89/m91-verified]
#pragma unroll
    for (int nt = 0; nt < NTW; ++nt) {
        const int col = tn * BN + wn * (BN / 2) + nt * 16 + l16;
        float bv = 0.f;
        if (EPI != 0) bv = bias[col];
#pragma unroll
        for (int mt = 0; mt < 4; ++mt) {
            const int row0 = tm * 128 + wm * 64 + mt * 16 + quad * 4;
#pragma unroll
            for (int j = 0; j < 4; ++j) {
                float v = acc[mt][nt][j];
                const size_t idx = (size_t)(row0 + j) * N + col;
                if (EPI == 1) {
                    v += bv + res[idx];
                    ((float*)Cv)[idx] = v;
                } else if (EPI == 2) {
                    v += bv;
                    v = 0.5f * v * (1.0f + erff(v * 0.70710678118654752f));
                    ((bf16*)Cv)[idx] = f2b(v);
                } else {
                    ((bf16*)Cv)[idx] = f2b(v);
                }
            }
        }
    }
}

// ---------------- MFMA flash attention (causal), XCD-local + 128-query tiles ----------
// Grid 256 (1-D): id = pair*32 + bh -> id%8 = bh%8, all 8 blocks of a head on one XCD
// (4 heads/XCD = 2 MB K/V, L2-resident). 512 threads, 8 waves x 16 q-rows = 128
// queries; pair p handles tiles {15-p, p} = uniform 34 chunks of 64 keys. K/V
// double-buffered, distance-1 prefetch, one barrier per chunk.
__global__ __launch_bounds__(512) void fattn_kernel(const bf16* __restrict__ QKV,
                                                    bf16* __restrict__ ctx) {
    const int id = blockIdx.x;
    const int pair = id >> 5;       // 0..7
    const int bh = id & 31;
    const int b = bh >> 4, h = bh & (H - 1);
    const int tid = threadIdx.x;
    const int wave = tid >> 6, lane = tid & 63;
    const int quad = lane >> 4, l16 = lane & 15;
    const bf16* Qp = QKV + (size_t)b * S * DQ + h * HD;
    const bf16* Kp = Qp + D;
    const bf16* Vp = Qp + 2 * D;

    __shared__ __align__(16) bf16 Ks[2][64 * 64];  // swizzled [key][dseg]
    __shared__ __align__(16) bf16 Vt[2][64][72];   // [d][key]
    __shared__ __align__(16) bf16 Ps[128][76];     // [q][key], wave-private rows

    // K staging: 1 slot (16B) per thread; slot = key*8 + (dseg ^ (key&7))
    const int keyA = tid >> 3, dsA = ((tid & 7) ^ (keyA & 7)) * 8;

    const int tiles[2] = {S / 128 - 1 - pair, pair};  // big tile first
#pragma unroll
    for (int ti = 0; ti < 2; ++ti) {
        const int t = tiles[ti];
        const int q0 = t * 128;
        // Q fragments (A-layout); wave w owns q-rows [w*16, w*16+16)
        const bf16* qg = Qp + (size_t)(q0 + wave * 16 + l16) * DQ + quad * 8;
        const bf16x8 aQ0 = *(const bf16x8*)(qg);
        const bf16x8 aQ1 = *(const bf16x8*)(qg + 32);

        f32x4 O[4];
#pragma unroll
        for (int nt = 0; nt < 4; ++nt) O[nt] = (f32x4){0.f, 0.f, 0.f, 0.f};
        float m[4] = {-3.0e38f, -3.0e38f, -3.0e38f, -3.0e38f};
        float l[4] = {0.f, 0.f, 0.f, 0.f};

        // pre-stage chunk 0 into buffer 0 (prev tile ends on buf1: nch even)
        __syncthreads();
        gld_lds16(Kp + (size_t)keyA * DQ + dsA, Ks[0] + tid * 8);
        {
            // V: wave w stages d in [w*8, w*8+8), key = lane
            const bf16* vg = Vp + (size_t)lane * DQ + wave * 8;
            union { int4 v; bf16 hh[8]; } u;
            u.v = *(const int4*)vg;
#pragma unroll
            for (int i = 0; i < 8; ++i) Vt[0][wave * 8 + i][lane] = u.hh[i];
        }

        const int nch = 2 * t + 2;
        for (int c = 0; c < nch; ++c) {
            const int cur = c & 1, nxt = cur ^ 1;
            __syncthreads();  // buf[cur] ready (drains prefetch vmcnt + V lgkm)
            // prefetch chunk c+1 into buf[nxt]
            union { int4 v; bf16 hh[8]; } u;
            if (c < nch - 1) {
                const int k1 = (c + 1) * 64;
                gld_lds16(Kp + (size_t)(k1 + keyA) * DQ + dsA, Ks[nxt] + tid * 8);
                u.v = *(const int4*)(Vp + (size_t)(k1 + lane) * DQ + wave * 8);
            }

            // scores: 16q x 64k per wave, scaled by 1/sqrt(64)
            f32x4 sc[4];
#pragma unroll
            for (int nt = 0; nt < 4; ++nt) {
                const int r = nt * 16 + l16;
                const bf16x8 bK0 = *(const bf16x8*)(Ks[cur] + (r * 8 + (quad ^ (r & 7))) * 8);
                const bf16x8 bK1 = *(const bf16x8*)(Ks[cur] + (r * 8 + ((4 + quad) ^ (r & 7))) * 8);
                f32x4 z = (f32x4){0.f, 0.f, 0.f, 0.f};
                z = __builtin_amdgcn_mfma_f32_16x16x32_bf16(aQ0, bK0, z, 0, 0, 0);
                z = __builtin_amdgcn_mfma_f32_16x16x32_bf16(aQ1, bK1, z, 0, 0, 0);
                sc[nt] = z;
            }
#pragma unroll
            for (int nt = 0; nt < 4; ++nt)
#pragma unroll
                for (int j = 0; j < 4; ++j) sc[nt][j] *= 0.125f;
            // causal mask — last two chunks intersect the 128-row diagonal band
            if (c >= 2 * t) {
                const int kbase = (c - 2 * t) * 64;
#pragma unroll
                for (int nt = 0; nt < 4; ++nt) {
                    const int rel_k = kbase + nt * 16 + l16;
#pragma unroll
                    for (int j = 0; j < 4; ++j)
                        if (rel_k > wave * 16 + quad * 4 + j) sc[nt][j] = -3.0e38f;
                }
            }
            // online softmax (rows = quad*4+j; reduce across 16 lanes)
            float al[4];
#pragma unroll
            for (int j = 0; j < 4; ++j) {
                float mx = fmaxf(fmaxf(sc[0][j], sc[1][j]), fmaxf(sc[2][j], sc[3][j]));
#pragma unroll
                for (int off = 1; off <= 8; off <<= 1) mx = fmaxf(mx, __shfl_xor(mx, off));
                const float mn = fmaxf(m[j], mx);
                al[j] = __expf(m[j] - mn);
                m[j] = mn;
                float rs = 0.f;
#pragma unroll
                for (int nt = 0; nt < 4; ++nt) {
                    sc[nt][j] = __expf(sc[nt][j] - mn);
                    rs += sc[nt][j];
                }
#pragma unroll
                for (int off = 1; off <= 8; off <<= 1) rs += __shfl_xor(rs, off);
                l[j] = l[j] * al[j] + rs;
            }
            // P: C-layout -> LDS -> A-layout (wave-private rows)
#pragma unroll
            for (int nt = 0; nt < 4; ++nt)
#pragma unroll
                for (int j = 0; j < 4; ++j)
                    Ps[wave * 16 + quad * 4 + j][nt * 16 + l16] = f2b(sc[nt][j]);
            asm volatile("s_waitcnt lgkmcnt(0)" ::: "memory");
            const bf16x8 aP0 = *(const bf16x8*)&Ps[wave * 16 + l16][quad * 8];
            const bf16x8 aP1 = *(const bf16x8*)&Ps[wave * 16 + l16][32 + quad * 8];
            // O = O*alpha + P V
#pragma unroll
            for (int nt = 0; nt < 4; ++nt)
#pragma unroll
                for (int j = 0; j < 4; ++j) O[nt][j] *= al[j];
#pragma unroll
            for (int nt = 0; nt < 4; ++nt) {
                const bf16x8 bV0 = *(const bf16x8*)&Vt[cur][nt * 16 + l16][quad * 8];
                const bf16x8 bV1 = *(const bf16x8*)&Vt[cur][nt * 16 + l16][32 + quad * 8];
                O[nt] = __builtin_amdgcn_mfma_f32_16x16x32_bf16(aP0, bV0, O[nt], 0, 0, 0);
                O[nt] = __builtin_amdgcn_mfma_f32_16x16x32_bf16(aP1, bV1, O[nt], 0, 0, 0);
            }
            // commit prefetched V into buf[nxt]
            if (c < nch - 1) {
#pragma unroll
                for (int i = 0; i < 8; ++i) Vt[nxt][wave * 8 + i][lane] = u.hh[i];
            }
        }

        // finalize: ctx compact [token][h*64+d], stride D
        const size_t hoC = (size_t)b * S * D + h * HD;
        float rl[4];
#pragma unroll
        for (int j = 0; j < 4; ++j) rl[j] = 1.0f / l[j];
#pragma unroll
        for (int nt = 0; nt < 4; ++nt)
#pragma unroll
            for (int j = 0; j < 4; ++j)
                ctx[hoC + (size_t)(q0 + wave * 16 + quad * 4 + j) * D + nt * 16 + l16] =
                    f2b(O[nt][j] * rl[j]);
    }
}

// ---------------- launcher ----------------
extern "C" void kernel_launch(void* const* d_in, const int* in_sizes, int n_in,
                              void* d_out, int out_size, void* d_ws, size_t ws_size,
                              hipStream_t stream) {
    const float* x     = (const float*)d_in[0];
    const float* ln1_g = (const float*)d_in[1];
    const float* ln1_b = (const float*)d_in[2];
    const float* Wq    = (const float*)d_in[3];
    const float* Wk    = (const float*)d_in[4];
    const float* Wv    = (const float*)d_in[5];
    const float* Wo    = (const float*)d_in[6];
    const float* bo    = (const float*)d_in[7];
    const float* ln2_g = (const float*)d_in[8];
    const float* ln2_b = (const float*)d_in[9];
    const float* W1    = (const float*)d_in[10];
    const float* b1    = (const float*)d_in[11];
    const float* W2    = (const float*)d_in[12];
    const float* b2    = (const float*)d_in[13];
    float* out = (float*)d_out;

    // workspace (MB), lifetime-overlapped; peak 64 MB:
    //   [ 0, 8): h (LN1 out)            -> W1T (conv after QKV gemm)
    //   [ 8,32): QKVb (packed, 24 MB)   \
    //   [32,40): ctx (attn out)          } -> hff [8,40) (32 MB)
    //   [40,48): h2 (LN2 out)
    //   [48,54): WqkvT   [54,56): WoT   [56,64): W2T
    //   x2 (fp32 residual) lives in d_out; final GEMM reads it in-place.
    char* ws = (char*)d_ws;
    const size_t MB = (size_t)1 << 20;
    bf16* h     = (bf16*)(ws + 0 * MB);
    bf16* W1T   = (bf16*)(ws + 0 * MB);
    bf16* QKVb  = (bf16*)(ws + 8 * MB);
    bf16* hff   = (bf16*)(ws + 8 * MB);
    bf16* ctx   = (bf16*)(ws + 32 * MB);
    bf16* h2    = (bf16*)(ws + 40 * MB);
    bf16* WqkvT = (bf16*)(ws + 48 * MB);
    bf16* WoT   = (bf16*)(ws + 54 * MB);
    bf16* W2T   = (bf16*)(ws + 56 * MB);

    // --- 0) transpose-convert weights (Wq/Wk/Wv fused into one B^T) ---
    dim3 gt(16, 16);
    convT_kernel<<<gt, 256, 0, stream>>>(Wq, WqkvT,                 D, D);
    convT_kernel<<<gt, 256, 0, stream>>>(Wk, WqkvT + (size_t)D * D, D, D);
    convT_kernel<<<gt, 256, 0, stream>>>(Wv, WqkvT + (size_t)2 * D * D, D, D);
    convT_kernel<<<gt, 256, 0, stream>>>(Wo, WoT, D, D);
    convT_kernel<<<dim3(64, 16), 256, 0, stream>>>(W2, W2T, DFF, D);
    // --- 1) LN1 ---
    ln_kernel<<<NR, 256, 0, stream>>>(x, ln1_g, ln1_b, h);
    // --- 2) QKV = h @ [Wq|Wk|Wv]   [4096,1024]x[1024,3072] ---
    gemm_bt<0, 128><<<(NR / 128) * (DQ / 128), 256, 0, stream>>>(
        h, WqkvT, nullptr, nullptr, QKVb, NR, DQ, D);
    // h dead now -> W1T into [0,8)
    convT_kernel<<<dim3(16, 64), 256, 0, stream>>>(W1, W1T, D, DFF);
    // --- 3) flash attention -> ctx ---
    fattn_kernel<<<dim3((S / 128 / 2) * B * H), 512, 0, stream>>>(QKVb, ctx);
    // --- 4) x2 = x + ctx @ Wo + bo   (fp32 into d_out) ---
    gemm_bt<1, 64><<<(NR / 128) * (D / 64), 256, 0, stream>>>(
        ctx, WoT, bo, x, out, NR, D, D);
    // --- 5) LN2 ---
    ln_kernel<<<NR, 256, 0, stream>>>(out, ln2_g, ln2_b, h2);
    // --- 6) hff = gelu(h2 @ W1 + b1)   [4096,1024]x[1024,4096] ---
    gemm_bt<2, 128><<<(NR / 128) * (DFF / 128), 256, 0, stream>>>(
        h2, W1T, b1, nullptr, hff, NR, DFF, D);
    // --- 7) out = x2 + hff @ W2 + b2   [4096,4096]x[4096,1024], in-place ---
    gemm_bt<1, 64><<<(NR / 128) * (D / 64), 256, 0, stream>>>(
        hff, W2T, b2, out, out, NR, D, DFF);
}

// Round 10
// 388.974 us; speedup vs baseline: 13.5475x; 1.0786x over previous
//
#include <hip/hip_runtime.h>
#include <hip/hip_bf16.h>
#include <math.h>

using bf16 = __hip_bfloat16;
typedef short bf16x8 __attribute__((ext_vector_type(8)));
typedef float f32x4 __attribute__((ext_vector_type(4)));

static constexpr int B = 2, S = 2048, D = 1024, H = 16, HD = 64, DFF = 4096;
static constexpr int NR = B * S;   // 4096 rows
static constexpr int DQ = 3072;    // packed QKV row stride
static constexpr float EPS = 1e-5f;

__device__ __forceinline__ bf16 f2b(float v) { return __float2bfloat16(v); }

// async global->LDS, 16B per lane; LDS dest must be wave-uniform base + lane*16
typedef __attribute__((address_space(1))) const void* gp1_t;
typedef __attribute__((address_space(3))) void* sp3_t;
__device__ __forceinline__ void gld_lds16(const bf16* g, bf16* l) {
    __builtin_amdgcn_global_load_lds((gp1_t)(const void*)g, (sp3_t)(void*)l, 16, 0, 0);
}

// ---------------- tiled transpose + fp32->bf16: dst[n][k] = src[k][n] ----------------
__global__ __launch_bounds__(256) void convT_kernel(const float* __restrict__ src, // [K][N]
                                                    bf16* __restrict__ dst,        // [N][K]
                                                    int K, int N) {
    __shared__ float tile[64][65];
    const int k0 = blockIdx.x * 64, n0 = blockIdx.y * 64;
    const int tid = threadIdx.x;
    const int r = tid >> 4, c = (tid & 15) * 4;
#pragma unroll
    for (int rr = 0; rr < 64; rr += 16) {
        float4 v = *(const float4*)&src[(size_t)(k0 + r + rr) * N + n0 + c];
        tile[r + rr][c] = v.x; tile[r + rr][c + 1] = v.y;
        tile[r + rr][c + 2] = v.z; tile[r + rr][c + 3] = v.w;
    }
    __syncthreads();
    const int n = tid >> 2, ks = (tid & 3) * 16;
    union { bf16 h[16]; int4 v2[2]; } o;
#pragma unroll
    for (int i = 0; i < 16; ++i) o.h[i] = f2b(tile[ks + i][n]);
    bf16* dp = &dst[(size_t)(n0 + n) * K + k0 + ks];
    *(int4*)dp = o.v2[0];
    *(int4*)(dp + 8) = o.v2[1];
}

// ---------------- LayerNorm: fp32 in, bf16 out; one block per row ----------------
__global__ __launch_bounds__(256) void ln_kernel(const float* __restrict__ x,
                                                 const float* __restrict__ g,
                                                 const float* __restrict__ b,
                                                 bf16* __restrict__ out) {
    const int row = blockIdx.x;
    const int tid = threadIdx.x;
    const float4 v4 = ((const float4*)(x + (size_t)row * D))[tid];
    float v[4] = {v4.x, v4.y, v4.z, v4.w};
    float s = v[0] + v[1] + v[2] + v[3];
    float sq = v[0] * v[0] + v[1] * v[1] + v[2] * v[2] + v[3] * v[3];
#pragma unroll
    for (int off = 32; off >= 1; off >>= 1) {
        s += __shfl_xor(s, off);
        sq += __shfl_xor(sq, off);
    }
    __shared__ float ssum[4], ssq[4];
    const int wave = tid >> 6;
    if ((tid & 63) == 0) { ssum[wave] = s; ssq[wave] = sq; }
    __syncthreads();
    s = ssum[0] + ssum[1] + ssum[2] + ssum[3];
    sq = ssq[0] + ssq[1] + ssq[2] + ssq[3];
    const float mu = s * (1.0f / D);
    const float var = sq * (1.0f / D) - mu * mu;
    const float rstd = rsqrtf(var + EPS);
    bf16* orow = out + (size_t)row * D;
#pragma unroll
    for (int i = 0; i < 4; ++i) {
        const int c = tid * 4 + i;
        orow[c] = f2b((v[i] - mu) * rstd * g[c] + b[c]);
    }
}

// ---------------- GEMM: C[M,N] = A[M,K] @ Bt[N,K]^T ----------------
// 1-D grid of Mtiles*(Ntiles/TPB) blocks; p -> tm = p % Mtiles (tm-fast: XCD gets
// few A strips, L2-resident), tn0 = (p / Mtiles) * TPB. Each block does TPB tiles
// (same tm, adjacent tn -> tile 2's A loads self-L2-hot; uniform work, no ragged
// generation tail). K-loop: LDS double-buffer, distance-1 prefetch across barrier.
// Epilogue (bf16 outs): stage C tile in LDS, re-read row-major, int4 stores.
// EPI 0: bf16 out. EPI 1: + fp32 bias + fp32 residual, fp32 out (res==C OK, direct).
// EPI 2: + fp32 bias + exact GELU, bf16 out.
// NOTE: no local arrays of LDS pointers (addrspacecast static-init is rejected on
// gfx950) — buffer bases are computed by index arithmetic at each use.
template <int EPI, int BN, int TPB>
__global__ __launch_bounds__(256) void gemm_bt(const bf16* __restrict__ A,
                                               const bf16* __restrict__ Bt,
                                               const float* __restrict__ bias,
                                               const float* __restrict__ res,
                                               void* __restrict__ Cv,
                                               int M, int N, int K) {
    constexpr int NTW = BN / 32;                    // n-tiles per wave
    constexpr int ASZ = 128 * 32, BSZ = BN * 32;    // elems per buffer
    constexpr int CST = BN + 8;                     // stage stride (16B-aligned rows)
    constexpr int BUFE = 2 * (ASZ + BSZ);
    constexpr int STGE = (EPI == 1) ? 0 : 128 * CST;
    constexpr int SMEM = BUFE > STGE ? BUFE : STGE;
    __shared__ __align__(16) bf16 smem[SMEM];
    // layout: A0 [0,ASZ), A1 [ASZ,2ASZ), B0 [2ASZ,2ASZ+BSZ), B1 [2ASZ+BSZ,...)

    const int Mtiles = M / 128;
    const int p = blockIdx.x;
    const int tm = p % Mtiles;
    const int tn0 = (p / Mtiles) * TPB;
    const int tid = threadIdx.x;
    const int wave = tid >> 6, lane = tid & 63;
    const int wm = wave >> 1, wn = wave & 1;
    const int quad = lane >> 4, l16 = lane & 15;

    // slot s (16B) <-> (row = s>>2, kseg = (s&3)*8)
    const int s_row = tid >> 2, s_seg = (tid & 3) * 8;
    const size_t K64 = (size_t)64 * K;
    const int nk = K / 32;

    for (int tp = 0; tp < TPB; ++tp) {
        const int tn = tn0 + tp;
        if (tp) __syncthreads();   // prior tile's stage reads done before DMA reuse

        f32x4 acc[4][NTW];
#pragma unroll
        for (int i = 0; i < 4; ++i)
#pragma unroll
            for (int j = 0; j < NTW; ++j) acc[i][j] = (f32x4){0.f, 0.f, 0.f, 0.f};

        const bf16* Ap = A + (size_t)(tm * 128 + s_row) * K + s_seg;
        const bf16* Bp = Bt + (size_t)(tn * BN + s_row) * K + s_seg;

        // prologue: slab 0 -> buf 0
        gld_lds16(Ap, smem + tid * 8);
        gld_lds16(Ap + K64, smem + (256 + tid) * 8);
        gld_lds16(Bp, smem + 2 * ASZ + tid * 8);
        if constexpr (BN == 128) gld_lds16(Bp + K64, smem + 2 * ASZ + (256 + tid) * 8);
        Ap += 32;
        Bp += 32;

        for (int kt = 0; kt < nk; ++kt) {
            const int cur = kt & 1, nxt = cur ^ 1;
            bf16* Acur = smem + cur * ASZ;
            bf16* Bcur = smem + 2 * ASZ + cur * BSZ;
            __syncthreads();  // drains prefetch issued one iteration ago
            if (kt + 1 < nk) {
                bf16* Anxt = smem + nxt * ASZ;
                bf16* Bnxt = smem + 2 * ASZ + nxt * BSZ;
                gld_lds16(Ap, Anxt + tid * 8);
                gld_lds16(Ap + K64, Anxt + (256 + tid) * 8);
                gld_lds16(Bp, Bnxt + tid * 8);
                if constexpr (BN == 128) gld_lds16(Bp + K64, Bnxt + (256 + tid) * 8);
                Ap += 32;
                Bp += 32;
            }

            bf16x8 aF[4], bF[NTW];
#pragma unroll
            for (int mt = 0; mt < 4; ++mt)
                aF[mt] = *(const bf16x8*)(Acur + (wm * 64 + mt * 16 + l16) * 32 + quad * 8);
#pragma unroll
            for (int nt = 0; nt < NTW; ++nt)
                bF[nt] = *(const bf16x8*)(Bcur + (wn * (BN / 2) + nt * 16 + l16) * 32 + quad * 8);
#pragma unroll
            for (int mt = 0; mt < 4; ++mt)
#pragma unroll
                for (int nt = 0; nt < NTW; ++nt)
                    acc[mt][nt] = __builtin_amdgcn_mfma_f32_16x16x32_bf16(
                        aF[mt], bF[nt], acc[mt][nt], 0, 0, 0);
        }

        // ---- epilogue.  C/D layout: col = lane&15, row = quad*4 + j ----
        if constexpr (EPI == 1) {
            // fp32 out + bias + residual, direct stores
#pragma unroll
            for (int nt = 0; nt < NTW; ++nt) {
                const int col = tn * BN + wn * (BN / 2) + nt * 16 + l16;
                const float bv = bias[col];
#pragma unroll
                for (int mt = 0; mt < 4; ++mt) {
                    const int row0 = tm * 128 + wm * 64 + mt * 16 + quad * 4;
#pragma unroll
                    for (int j = 0; j < 4; ++j) {
                        const size_t idx = (size_t)(row0 + j) * N + col;
                        ((float*)Cv)[idx] = acc[mt][nt][j] + bv + res[idx];
                    }
                }
            }
        } else {
            // bf16 out (EPI 0: plain, EPI 2: bias+GELU): stage in LDS, int4 stores
            __syncthreads();  // all waves done reading A/B bufs of last slab
#pragma unroll
            for (int nt = 0; nt < NTW; ++nt) {
                const int ccol = wn * (BN / 2) + nt * 16 + l16;
                float bv = 0.f;
                if (EPI == 2) bv = bias[tn * BN + ccol];
#pragma unroll
                for (int mt = 0; mt < 4; ++mt) {
                    const int r0 = wm * 64 + mt * 16 + quad * 4;
#pragma unroll
                    for (int j = 0; j < 4; ++j) {
                        float v = acc[mt][nt][j];
                        if (EPI == 2) {
                            v += bv;
                            v = 0.5f * v * (1.0f + erff(v * 0.70710678118654752f));
                        }
                        smem[(r0 + j) * CST + ccol] = f2b(v);
                    }
                }
            }
            __syncthreads();
            // coalesced write-out: 16*BN int4 total, BN/16 per thread
            constexpr int NI4 = BN / 16;
            bf16* crow = (bf16*)Cv + (size_t)(tm * 128) * N + tn * BN;
#pragma unroll
            for (int i = 0; i < NI4; ++i) {
                const int gid = i * 256 + tid;
                const int row = gid / (BN / 8), c8 = gid % (BN / 8);
                const int4 val = *(const int4*)(smem + row * CST + c8 * 8);
                *(int4*)(crow + (size_t)row * N + c8 * 8) = val;
            }
        }
    }
}

// ---------------- MFMA flash attention (causal), XCD-local + 128-query tiles ----------
// Grid 256 (1-D): id = pair*32 + bh -> id%8 = bh%8, all 8 blocks of a head on one XCD
// (4 heads/XCD = 2 MB K/V, L2-resident). 512 threads, 8 waves x 16 q-rows = 128
// queries; pair p handles tiles {15-p, p} = uniform 34 chunks of 64 keys. K/V
// double-buffered, distance-1 prefetch, one barrier per chunk.
__global__ __launch_bounds__(512) void fattn_kernel(const bf16* __restrict__ QKV,
                                                    bf16* __restrict__ ctx) {
    const int id = blockIdx.x;
    const int pair = id >> 5;       // 0..7
    const int bh = id & 31;
    const int b = bh >> 4, h = bh & (H - 1);
    const int tid = threadIdx.x;
    const int wave = tid >> 6, lane = tid & 63;
    const int quad = lane >> 4, l16 = lane & 15;
    const bf16* Qp = QKV + (size_t)b * S * DQ + h * HD;
    const bf16* Kp = Qp + D;
    const bf16* Vp = Qp + 2 * D;

    __shared__ __align__(16) bf16 Ks[2][64 * 64];  // swizzled [key][dseg]
    __shared__ __align__(16) bf16 Vt[2][64][72];   // [d][key]
    __shared__ __align__(16) bf16 Ps[128][76];     // [q][key], wave-private rows

    // K staging: 1 slot (16B) per thread; slot = key*8 + (dseg ^ (key&7))
    const int keyA = tid >> 3, dsA = ((tid & 7) ^ (keyA & 7)) * 8;

    const int tiles[2] = {S / 128 - 1 - pair, pair};  // big tile first
#pragma unroll
    for (int ti = 0; ti < 2; ++ti) {
        const int t = tiles[ti];
        const int q0 = t * 128;
        // Q fragments (A-layout); wave w owns q-rows [w*16, w*16+16)
        const bf16* qg = Qp + (size_t)(q0 + wave * 16 + l16) * DQ + quad * 8;
        const bf16x8 aQ0 = *(const bf16x8*)(qg);
        const bf16x8 aQ1 = *(const bf16x8*)(qg + 32);

        f32x4 O[4];
#pragma unroll
        for (int nt = 0; nt < 4; ++nt) O[nt] = (f32x4){0.f, 0.f, 0.f, 0.f};
        float m[4] = {-3.0e38f, -3.0e38f, -3.0e38f, -3.0e38f};
        float l[4] = {0.f, 0.f, 0.f, 0.f};

        // pre-stage chunk 0 into buffer 0 (prev tile ends on buf1: nch even)
        __syncthreads();
        gld_lds16(Kp + (size_t)keyA * DQ + dsA, Ks[0] + tid * 8);
        {
            // V: wave w stages d in [w*8, w*8+8), key = lane
            const bf16* vg = Vp + (size_t)lane * DQ + wave * 8;
            union { int4 v; bf16 hh[8]; } u;
            u.v = *(const int4*)vg;
#pragma unroll
            for (int i = 0; i < 8; ++i) Vt[0][wave * 8 + i][lane] = u.hh[i];
        }

        const int nch = 2 * t + 2;
        for (int c = 0; c < nch; ++c) {
            const int cur = c & 1, nxt = cur ^ 1;
            __syncthreads();  // buf[cur] ready (drains prefetch vmcnt + V lgkm)
            // prefetch chunk c+1 into buf[nxt]
            union { int4 v; bf16 hh[8]; } u;
            if (c < nch - 1) {
                const int k1 = (c + 1) * 64;
                gld_lds16(Kp + (size_t)(k1 + keyA) * DQ + dsA, Ks[nxt] + tid * 8);
                u.v = *(const int4*)(Vp + (size_t)(k1 + lane) * DQ + wave * 8);
            }

            // scores: 16q x 64k per wave, scaled by 1/sqrt(64)
            f32x4 sc[4];
#pragma unroll
            for (int nt = 0; nt < 4; ++nt) {
                const int r = nt * 16 + l16;
                const bf16x8 bK0 = *(const bf16x8*)(Ks[cur] + (r * 8 + (quad ^ (r & 7))) * 8);
                const bf16x8 bK1 = *(const bf16x8*)(Ks[cur] + (r * 8 + ((4 + quad) ^ (r & 7))) * 8);
                f32x4 z = (f32x4){0.f, 0.f, 0.f, 0.f};
                z = __builtin_amdgcn_mfma_f32_16x16x32_bf16(aQ0, bK0, z, 0, 0, 0);
                z = __builtin_amdgcn_mfma_f32_16x16x32_bf16(aQ1, bK1, z, 0, 0, 0);
                sc[nt] = z;
            }
#pragma unroll
            for (int nt = 0; nt < 4; ++nt)
#pragma unroll
                for (int j = 0; j < 4; ++j) sc[nt][j] *= 0.125f;
            // causal mask — last two chunks intersect the 128-row diagonal band
            if (c >= 2 * t) {
                const int kbase = (c - 2 * t) * 64;
#pragma unroll
                for (int nt = 0; nt < 4; ++nt) {
                    const int rel_k = kbase + nt * 16 + l16;
#pragma unroll
                    for (int j = 0; j < 4; ++j)
                        if (rel_k > wave * 16 + quad * 4 + j) sc[nt][j] = -3.0e38f;
                }
            }
            // online softmax (rows = quad*4+j; reduce across 16 lanes)
            float al[4];
#pragma unroll
            for (int j = 0; j < 4; ++j) {
                float mx = fmaxf(fmaxf(sc[0][j], sc[1][j]), fmaxf(sc[2][j], sc[3][j]));
#pragma unroll
                for (int off = 1; off <= 8; off <<= 1) mx = fmaxf(mx, __shfl_xor(mx, off));
                const float mn = fmaxf(m[j], mx);
                al[j] = __expf(m[j] - mn);
                m[j] = mn;
                float rs = 0.f;
#pragma unroll
                for (int nt = 0; nt < 4; ++nt) {
                    sc[nt][j] = __expf(sc[nt][j] - mn);
                    rs += sc[nt][j];
                }
#pragma unroll
                for (int off = 1; off <= 8; off <<= 1) rs += __shfl_xor(rs, off);
                l[j] = l[j] * al[j] + rs;
            }
            // P: C-layout -> LDS -> A-layout (wave-private rows)
#pragma unroll
            for (int nt = 0; nt < 4; ++nt)
#pragma unroll
                for (int j = 0; j < 4; ++j)
                    Ps[wave * 16 + quad * 4 + j][nt * 16 + l16] = f2b(sc[nt][j]);
            asm volatile("s_waitcnt lgkmcnt(0)" ::: "memory");
            const bf16x8 aP0 = *(const bf16x8*)&Ps[wave * 16 + l16][quad * 8];
            const bf16x8 aP1 = *(const bf16x8*)&Ps[wave * 16 + l16][32 + quad * 8];
            // O = O*alpha + P V
#pragma unroll
            for (int nt = 0; nt < 4; ++nt)
#pragma unroll
                for (int j = 0; j < 4; ++j) O[nt][j] *= al[j];
#pragma unroll
            for (int nt = 0; nt < 4; ++nt) {
                const bf16x8 bV0 = *(const bf16x8*)&Vt[cur][nt * 16 + l16][quad * 8];
                const bf16x8 bV1 = *(const bf16x8*)&Vt[cur][nt * 16 + l16][32 + quad * 8];
                O[nt] = __builtin_amdgcn_mfma_f32_16x16x32_bf16(aP0, bV0, O[nt], 0, 0, 0);
                O[nt] = __builtin_amdgcn_mfma_f32_16x16x32_bf16(aP1, bV1, O[nt], 0, 0, 0);
            }
            // commit prefetched V into buf[nxt]
            if (c < nch - 1) {
#pragma unroll
                for (int i = 0; i < 8; ++i) Vt[nxt][wave * 8 + i][lane] = u.hh[i];
            }
        }

        // finalize: ctx compact [token][h*64+d], stride D
        const size_t hoC = (size_t)b * S * D + h * HD;
        float rl[4];
#pragma unroll
        for (int j = 0; j < 4; ++j) rl[j] = 1.0f / l[j];
#pragma unroll
        for (int nt = 0; nt < 4; ++nt)
#pragma unroll
            for (int j = 0; j < 4; ++j)
                ctx[hoC + (size_t)(q0 + wave * 16 + quad * 4 + j) * D + nt * 16 + l16] =
                    f2b(O[nt][j] * rl[j]);
    }
}

// ---------------- launcher ----------------
extern "C" void kernel_launch(void* const* d_in, const int* in_sizes, int n_in,
                              void* d_out, int out_size, void* d_ws, size_t ws_size,
                              hipStream_t stream) {
    const float* x     = (const float*)d_in[0];
    const float* ln1_g = (const float*)d_in[1];
    const float* ln1_b = (const float*)d_in[2];
    const float* Wq    = (const float*)d_in[3];
    const float* Wk    = (const float*)d_in[4];
    const float* Wv    = (const float*)d_in[5];
    const float* Wo    = (const float*)d_in[6];
    const float* bo    = (const float*)d_in[7];
    const float* ln2_g = (const float*)d_in[8];
    const float* ln2_b = (const float*)d_in[9];
    const float* W1    = (const float*)d_in[10];
    const float* b1    = (const float*)d_in[11];
    const float* W2    = (const float*)d_in[12];
    const float* b2    = (const float*)d_in[13];
    float* out = (float*)d_out;

    // workspace (MB), lifetime-overlapped; peak 64 MB:
    //   [ 0, 8): h (LN1 out)            -> W1T (conv after QKV gemm)
    //   [ 8,32): QKVb (packed, 24 MB)   \
    //   [32,40): ctx (attn out)          } -> hff [8,40) (32 MB)
    //   [40,48): h2 (LN2 out)
    //   [48,54): WqkvT   [54,56): WoT   [56,64): W2T
    //   x2 (fp32 residual) lives in d_out; final GEMM reads it in-place.
    char* ws = (char*)d_ws;
    const size_t MB = (size_t)1 << 20;
    bf16* h     = (bf16*)(ws + 0 * MB);
    bf16* W1T   = (bf16*)(ws + 0 * MB);
    bf16* QKVb  = (bf16*)(ws + 8 * MB);
    bf16* hff   = (bf16*)(ws + 8 * MB);
    bf16* ctx   = (bf16*)(ws + 32 * MB);
    bf16* h2    = (bf16*)(ws + 40 * MB);
    bf16* WqkvT = (bf16*)(ws + 48 * MB);
    bf16* WoT   = (bf16*)(ws + 54 * MB);
    bf16* W2T   = (bf16*)(ws + 56 * MB);

    // --- 0) transpose-convert weights (Wq/Wk/Wv fused into one B^T) ---
    dim3 gt(16, 16);
    convT_kernel<<<gt, 256, 0, stream>>>(Wq, WqkvT,                 D, D);
    convT_kernel<<<gt, 256, 0, stream>>>(Wk, WqkvT + (size_t)D * D, D, D);
    convT_kernel<<<gt, 256, 0, stream>>>(Wv, WqkvT + (size_t)2 * D * D, D, D);
    convT_kernel<<<gt, 256, 0, stream>>>(Wo, WoT, D, D);
    convT_kernel<<<dim3(64, 16), 256, 0, stream>>>(W2, W2T, DFF, D);
    // --- 1) LN1 ---
    ln_kernel<<<NR, 256, 0, stream>>>(x, ln1_g, ln1_b, h);
    // --- 2) QKV = h @ [Wq|Wk|Wv]   [4096,1024]x[1024,3072], 768 blocks (3/CU) ---
    gemm_bt<0, 128, 1><<<(NR / 128) * (DQ / 128), 256, 0, stream>>>(
        h, WqkvT, nullptr, nullptr, QKVb, NR, DQ, D);
    // h dead now -> W1T into [0,8)
    convT_kernel<<<dim3(16, 64), 256, 0, stream>>>(W1, W1T, D, DFF);
    // --- 3) flash attention -> ctx ---
    fattn_kernel<<<dim3((S / 128 / 2) * B * H), 512, 0, stream>>>(QKVb, ctx);
    // --- 4) x2 = x + ctx @ Wo + bo   (fp32 into d_out), 512 blocks ---
    gemm_bt<1, 64, 1><<<(NR / 128) * (D / 64), 256, 0, stream>>>(
        ctx, WoT, bo, x, out, NR, D, D);
    // --- 5) LN2 ---
    ln_kernel<<<NR, 256, 0, stream>>>(out, ln2_g, ln2_b, h2);
    // --- 6) hff = gelu(h2 @ W1 + b1), 512 persistent blocks x 2 tiles ---
    gemm_bt<2, 128, 2><<<(NR / 128) * (DFF / 128) / 2, 256, 0, stream>>>(
        h2, W1T, b1, nullptr, hff, NR, DFF, D);
    // --- 7) out = x2 + hff @ W2 + b2   [4096,4096]x[4096,1024], in-place ---
    gemm_bt<1, 64, 1><<<(NR / 128) * (D / 64), 256, 0, stream>>>(
        hff, W2T, b2, out, out, NR, D, DFF);
}

// Round 11
// 382.068 us; speedup vs baseline: 13.7924x; 1.0181x over previous
//
#include <hip/hip_runtime.h>
#include <hip/hip_bf16.h>
#include <math.h>

using bf16 = __hip_bfloat16;
typedef short bf16x8 __attribute__((ext_vector_type(8)));
typedef float f32x4 __attribute__((ext_vector_type(4)));

static constexpr int B = 2, S = 2048, D = 1024, H = 16, HD = 64, DFF = 4096;
static constexpr int NR = B * S;   // 4096 rows
static constexpr int DQ = 3072;    // packed QKV row stride
static constexpr float EPS = 1e-5f;

__device__ __forceinline__ bf16 f2b(float v) { return __float2bfloat16(v); }

// async global->LDS, 16B per lane; LDS dest must be wave-uniform base + lane*16
typedef __attribute__((address_space(1))) const void* gp1_t;
typedef __attribute__((address_space(3))) void* sp3_t;
__device__ __forceinline__ void gld_lds16(const bf16* g, bf16* l) {
    __builtin_amdgcn_global_load_lds((gp1_t)(const void*)g, (sp3_t)(void*)l, 16, 0, 0);
}

// ---------------- tiled transpose + fp32->bf16: dst[n][k] = src[k][n] ----------------
__global__ __launch_bounds__(256) void convT_kernel(const float* __restrict__ src, // [K][N]
                                                    bf16* __restrict__ dst,        // [N][K]
                                                    int K, int N) {
    __shared__ float tile[64][65];
    const int k0 = blockIdx.x * 64, n0 = blockIdx.y * 64;
    const int tid = threadIdx.x;
    const int r = tid >> 4, c = (tid & 15) * 4;
#pragma unroll
    for (int rr = 0; rr < 64; rr += 16) {
        float4 v = *(const float4*)&src[(size_t)(k0 + r + rr) * N + n0 + c];
        tile[r + rr][c] = v.x; tile[r + rr][c + 1] = v.y;
        tile[r + rr][c + 2] = v.z; tile[r + rr][c + 3] = v.w;
    }
    __syncthreads();
    const int n = tid >> 2, ks = (tid & 3) * 16;
    union { bf16 h[16]; int4 v2[2]; } o;
#pragma unroll
    for (int i = 0; i < 16; ++i) o.h[i] = f2b(tile[ks + i][n]);
    bf16* dp = &dst[(size_t)(n0 + n) * K + k0 + ks];
    *(int4*)dp = o.v2[0];
    *(int4*)(dp + 8) = o.v2[1];
}

// ---------------- LayerNorm: fp32 in, bf16 out; one block per row ----------------
__global__ __launch_bounds__(256) void ln_kernel(const float* __restrict__ x,
                                                 const float* __restrict__ g,
                                                 const float* __restrict__ b,
                                                 bf16* __restrict__ out) {
    const int row = blockIdx.x;
    const int tid = threadIdx.x;
    const float4 v4 = ((const float4*)(x + (size_t)row * D))[tid];
    float v[4] = {v4.x, v4.y, v4.z, v4.w};
    float s = v[0] + v[1] + v[2] + v[3];
    float sq = v[0] * v[0] + v[1] * v[1] + v[2] * v[2] + v[3] * v[3];
#pragma unroll
    for (int off = 32; off >= 1; off >>= 1) {
        s += __shfl_xor(s, off);
        sq += __shfl_xor(sq, off);
    }
    __shared__ float ssum[4], ssq[4];
    const int wave = tid >> 6;
    if ((tid & 63) == 0) { ssum[wave] = s; ssq[wave] = sq; }
    __syncthreads();
    s = ssum[0] + ssum[1] + ssum[2] + ssum[3];
    sq = ssq[0] + ssq[1] + ssq[2] + ssq[3];
    const float mu = s * (1.0f / D);
    const float var = sq * (1.0f / D) - mu * mu;
    const float rstd = rsqrtf(var + EPS);
    bf16* orow = out + (size_t)row * D;
#pragma unroll
    for (int i = 0; i < 4; ++i) {
        const int c = tid * 4 + i;
        orow[c] = f2b((v[i] - mu) * rstd * g[c] + b[c]);
    }
}

// ---------------- GEMM-256: C[M,N] = A @ Bt^T, 256x128 tile, 512 thr, bf16 out ----
// 8 waves in 4x2 (wm=wave>>1 owns rows wm*64.., wn=wave&1 owns cols wn*64..).
// 2 blocks/CU -> 16 waves/CU (50% occ). LDS dbuf, distance-1 prefetch across the
// barrier. Epilogue: stage 128-row halves in LDS, int4 coalesced stores.
// EPI 0: plain. EPI 2: + fp32 bias + exact GELU.
template <int EPI>
__global__ __launch_bounds__(512) void gemm256(const bf16* __restrict__ A,
                                               const bf16* __restrict__ Bt,
                                               const float* __restrict__ bias,
                                               bf16* __restrict__ C,
                                               int M, int N, int K) {
    constexpr int ASZ = 256 * 32, BSZ = 128 * 32;   // elems per buffer
    constexpr int CST = 128 + 8;                    // epilogue stage stride
    __shared__ __align__(16) bf16 smem[2 * (ASZ + BSZ)];  // 48 KB
    // A0 [0,ASZ) A1 [ASZ,2ASZ) B0 [2ASZ,2ASZ+BSZ) B1 [2ASZ+BSZ, ...)

    const int Mtiles = M / 256;
    const int p = blockIdx.x;
    const int tm = p % Mtiles;          // tm-fast: few A strips per XCD
    const int tn = p / Mtiles;
    const int tid = threadIdx.x;
    const int wave = tid >> 6, lane = tid & 63;
    const int wm = wave >> 1, wn = wave & 1;
    const int quad = lane >> 4, l16 = lane & 15;

    f32x4 acc[4][4];
#pragma unroll
    for (int i = 0; i < 4; ++i)
#pragma unroll
        for (int j = 0; j < 4; ++j) acc[i][j] = (f32x4){0.f, 0.f, 0.f, 0.f};

    // A: 1024 slots (2/thread: tid, tid+512); B: 512 slots. slot -> row=s>>2, seg=(s&3)*8
    const int s_row = tid >> 2, s_seg = (tid & 3) * 8;
    const bf16* ApLo = A + (size_t)(tm * 256 + s_row) * K + s_seg;
    const size_t K128 = (size_t)128 * K;
    const bf16* Bp = Bt + (size_t)(tn * 128 + s_row) * K + s_seg;

    // prologue: slab 0 -> buf 0
    gld_lds16(ApLo, smem + tid * 8);
    gld_lds16(ApLo + K128, smem + (512 + tid) * 8);
    gld_lds16(Bp, smem + 2 * ASZ + tid * 8);
    ApLo += 32;
    Bp += 32;

    const int nk = K / 32;
    for (int kt = 0; kt < nk; ++kt) {
        const int cur = kt & 1, nxt = cur ^ 1;
        bf16* Acur = smem + cur * ASZ;
        bf16* Bcur = smem + 2 * ASZ + cur * BSZ;
        __syncthreads();  // drains prefetch issued one full iteration ago
        if (kt + 1 < nk) {
            bf16* Anxt = smem + nxt * ASZ;
            bf16* Bnxt = smem + 2 * ASZ + nxt * BSZ;
            gld_lds16(ApLo, Anxt + tid * 8);
            gld_lds16(ApLo + K128, Anxt + (512 + tid) * 8);
            gld_lds16(Bp, Bnxt + tid * 8);
            ApLo += 32;
            Bp += 32;
        }

        bf16x8 aF[4], bF[4];
#pragma unroll
        for (int mt = 0; mt < 4; ++mt)
            aF[mt] = *(const bf16x8*)(Acur + (wm * 64 + mt * 16 + l16) * 32 + quad * 8);
#pragma unroll
        for (int nt = 0; nt < 4; ++nt)
            bF[nt] = *(const bf16x8*)(Bcur + (wn * 64 + nt * 16 + l16) * 32 + quad * 8);
#pragma unroll
        for (int mt = 0; mt < 4; ++mt)
#pragma unroll
            for (int nt = 0; nt < 4; ++nt)
                acc[mt][nt] = __builtin_amdgcn_mfma_f32_16x16x32_bf16(
                    aF[mt], bF[nt], acc[mt][nt], 0, 0, 0);
    }

    // epilogue in two 128-row halves. C/D layout: col = lane&15, row = quad*4+j.
#pragma unroll
    for (int hh = 0; hh < 2; ++hh) {
        __syncthreads();  // prev reads (k-loop or prev half's write-out) done
        if ((wm >> 1) == hh) {
#pragma unroll
            for (int nt = 0; nt < 4; ++nt) {
                const int ccol = wn * 64 + nt * 16 + l16;
                float bv = 0.f;
                if (EPI == 2) bv = bias[tn * 128 + ccol];
#pragma unroll
                for (int mt = 0; mt < 4; ++mt) {
                    const int r0 = (wm & 1) * 64 + mt * 16 + quad * 4;
#pragma unroll
                    for (int j = 0; j < 4; ++j) {
                        float v = acc[mt][nt][j];
                        if (EPI == 2) {
                            v += bv;
                            v = 0.5f * v * (1.0f + erff(v * 0.70710678118654752f));
                        }
                        smem[(r0 + j) * CST + ccol] = f2b(v);
                    }
                }
            }
        }
        __syncthreads();
        // write-out: 128x128 half-tile = 2048 int4; 4 per thread
        bf16* crow = C + (size_t)(tm * 256 + hh * 128) * N + tn * 128;
#pragma unroll
        for (int i = 0; i < 4; ++i) {
            const int gid = i * 512 + tid;
            const int row = gid >> 4, c8 = gid & 15;
            const int4 val = *(const int4*)(smem + row * CST + c8 * 8);
            *(int4*)(crow + (size_t)row * N + c8 * 8) = val;
        }
    }
}

// ---------------- GEMM: C[M,N] = A[M,K] @ Bt[N,K]^T  (128xBN, 256 thr) ----------
// EPI 1: + fp32 bias + fp32 residual, fp32 out (res==C in-place OK). Used for
// Wo and W2 (N=1024 -> grid 512 = 2 blocks/CU).
template <int EPI, int BN, int TPB>
__global__ __launch_bounds__(256) void gemm_bt(const bf16* __restrict__ A,
                                               const bf16* __restrict__ Bt,
                                               const float* __restrict__ bias,
                                               const float* __restrict__ res,
                                               void* __restrict__ Cv,
                                               int M, int N, int K) {
    constexpr int NTW = BN / 32;
    constexpr int ASZ = 128 * 32, BSZ = BN * 32;
    __shared__ __align__(16) bf16 smem[2 * (ASZ + BSZ)];

    const int Mtiles = M / 128;
    const int p = blockIdx.x;
    const int tm = p % Mtiles;
    const int tn0 = (p / Mtiles) * TPB;
    const int tid = threadIdx.x;
    const int wave = tid >> 6, lane = tid & 63;
    const int wm = wave >> 1, wn = wave & 1;
    const int quad = lane >> 4, l16 = lane & 15;

    const int s_row = tid >> 2, s_seg = (tid & 3) * 8;
    const size_t K64 = (size_t)64 * K;
    const int nk = K / 32;

    for (int tp = 0; tp < TPB; ++tp) {
        const int tn = tn0 + tp;
        if (tp) __syncthreads();

        f32x4 acc[4][NTW];
#pragma unroll
        for (int i = 0; i < 4; ++i)
#pragma unroll
            for (int j = 0; j < NTW; ++j) acc[i][j] = (f32x4){0.f, 0.f, 0.f, 0.f};

        const bf16* Ap = A + (size_t)(tm * 128 + s_row) * K + s_seg;
        const bf16* Bp = Bt + (size_t)(tn * BN + s_row) * K + s_seg;

        gld_lds16(Ap, smem + tid * 8);
        gld_lds16(Ap + K64, smem + (256 + tid) * 8);
        gld_lds16(Bp, smem + 2 * ASZ + tid * 8);
        if constexpr (BN == 128) gld_lds16(Bp + K64, smem + 2 * ASZ + (256 + tid) * 8);
        Ap += 32;
        Bp += 32;

        for (int kt = 0; kt < nk; ++kt) {
            const int cur = kt & 1, nxt = cur ^ 1;
            bf16* Acur = smem + cur * ASZ;
            bf16* Bcur = smem + 2 * ASZ + cur * BSZ;
            __syncthreads();
            if (kt + 1 < nk) {
                bf16* Anxt = smem + nxt * ASZ;
                bf16* Bnxt = smem + 2 * ASZ + nxt * BSZ;
                gld_lds16(Ap, Anxt + tid * 8);
                gld_lds16(Ap + K64, Anxt + (256 + tid) * 8);
                gld_lds16(Bp, Bnxt + tid * 8);
                if constexpr (BN == 128) gld_lds16(Bp + K64, Bnxt + (256 + tid) * 8);
                Ap += 32;
                Bp += 32;
            }

            bf16x8 aF[4], bF[NTW];
#pragma unroll
            for (int mt = 0; mt < 4; ++mt)
                aF[mt] = *(const bf16x8*)(Acur + (wm * 64 + mt * 16 + l16) * 32 + quad * 8);
#pragma unroll
            for (int nt = 0; nt < NTW; ++nt)
                bF[nt] = *(const bf16x8*)(Bcur + (wn * (BN / 2) + nt * 16 + l16) * 32 + quad * 8);
#pragma unroll
            for (int mt = 0; mt < 4; ++mt)
#pragma unroll
                for (int nt = 0; nt < NTW; ++nt)
                    acc[mt][nt] = __builtin_amdgcn_mfma_f32_16x16x32_bf16(
                        aF[mt], bF[nt], acc[mt][nt], 0, 0, 0);
        }

        // EPI 1 epilogue: fp32 + bias + residual, direct stores
#pragma unroll
        for (int nt = 0; nt < NTW; ++nt) {
            const int col = tn * BN + wn * (BN / 2) + nt * 16 + l16;
            const float bv = bias[col];
#pragma unroll
            for (int mt = 0; mt < 4; ++mt) {
                const int row0 = tm * 128 + wm * 64 + mt * 16 + quad * 4;
#pragma unroll
                for (int j = 0; j < 4; ++j) {
                    const size_t idx = (size_t)(row0 + j) * N + col;
                    ((float*)Cv)[idx] = acc[mt][nt][j] + bv + res[idx];
                }
            }
        }
    }
}

// ---------------- MFMA flash attention (causal), 2 blocks/CU ----------
// Grid 512 (1-D): bh = id&31 (id%8 = bh%8 -> per-head XCD locality), k = id>>5,
// t = k<8 ? 15-k : k-8 (snake: co-resident pairs sum to 34 chunks; big tiles
// dispatched first). 512 threads = 8 waves x 16 q-rows = one 128-query tile.
// K/V double-buffered, distance-1 prefetch, one barrier per 64-key chunk.
__global__ __launch_bounds__(512) void fattn_kernel(const bf16* __restrict__ QKV,
                                                    bf16* __restrict__ ctx) {
    const int id = blockIdx.x;
    const int bh = id & 31;
    const int k = id >> 5;          // 0..15
    const int t = (k < 8) ? 15 - k : k - 8;
    const int b = bh >> 4, h = bh & (H - 1);
    const int tid = threadIdx.x;
    const int wave = tid >> 6, lane = tid & 63;
    const int quad = lane >> 4, l16 = lane & 15;
    const bf16* Qp = QKV + (size_t)b * S * DQ + h * HD;
    const bf16* Kp = Qp + D;
    const bf16* Vp = Qp + 2 * D;

    __shared__ __align__(16) bf16 Ks[2][64 * 64];  // swizzled [key][dseg]
    __shared__ __align__(16) bf16 Vt[2][64][72];   // [d][key]
    __shared__ __align__(16) bf16 Ps[128][76];     // [q][key], wave-private rows

    // K staging: 1 slot (16B) per thread; slot = key*8 + (dseg ^ (key&7))
    const int keyA = tid >> 3, dsA = ((tid & 7) ^ (keyA & 7)) * 8;

    const int q0 = t * 128;
    // Q fragments (A-layout); wave w owns q-rows [w*16, w*16+16)
    const bf16* qg = Qp + (size_t)(q0 + wave * 16 + l16) * DQ + quad * 8;
    const bf16x8 aQ0 = *(const bf16x8*)(qg);
    const bf16x8 aQ1 = *(const bf16x8*)(qg + 32);

    f32x4 O[4];
#pragma unroll
    for (int nt = 0; nt < 4; ++nt) O[nt] = (f32x4){0.f, 0.f, 0.f, 0.f};
    float m[4] = {-3.0e38f, -3.0e38f, -3.0e38f, -3.0e38f};
    float l[4] = {0.f, 0.f, 0.f, 0.f};

    // pre-stage chunk 0 into buffer 0
    gld_lds16(Kp + (size_t)keyA * DQ + dsA, Ks[0] + tid * 8);
    {
        // V: wave w stages d in [w*8, w*8+8), key = lane
        const bf16* vg = Vp + (size_t)lane * DQ + wave * 8;
        union { int4 v; bf16 hh[8]; } u;
        u.v = *(const int4*)vg;
#pragma unroll
        for (int i = 0; i < 8; ++i) Vt[0][wave * 8 + i][lane] = u.hh[i];
    }

    const int nch = 2 * t + 2;
    for (int c = 0; c < nch; ++c) {
        const int cur = c & 1, nxt = cur ^ 1;
        __syncthreads();  // buf[cur] ready (drains prefetch vmcnt + V lgkm)
        // prefetch chunk c+1 into buf[nxt]
        union { int4 v; bf16 hh[8]; } u;
        if (c < nch - 1) {
            const int k1 = (c + 1) * 64;
            gld_lds16(Kp + (size_t)(k1 + keyA) * DQ + dsA, Ks[nxt] + tid * 8);
            u.v = *(const int4*)(Vp + (size_t)(k1 + lane) * DQ + wave * 8);
        }

        // scores: 16q x 64k per wave, scaled by 1/sqrt(64)
        f32x4 sc[4];
#pragma unroll
        for (int nt = 0; nt < 4; ++nt) {
            const int r = nt * 16 + l16;
            const bf16x8 bK0 = *(const bf16x8*)(Ks[cur] + (r * 8 + (quad ^ (r & 7))) * 8);
            const bf16x8 bK1 = *(const bf16x8*)(Ks[cur] + (r * 8 + ((4 + quad) ^ (r & 7))) * 8);
            f32x4 z = (f32x4){0.f, 0.f, 0.f, 0.f};
            z = __builtin_amdgcn_mfma_f32_16x16x32_bf16(aQ0, bK0, z, 0, 0, 0);
            z = __builtin_amdgcn_mfma_f32_16x16x32_bf16(aQ1, bK1, z, 0, 0, 0);
            sc[nt] = z;
        }
#pragma unroll
        for (int nt = 0; nt < 4; ++nt)
#pragma unroll
            for (int j = 0; j < 4; ++j) sc[nt][j] *= 0.125f;
        // causal mask — last two chunks intersect the 128-row diagonal band
        if (c >= 2 * t) {
            const int kbase = (c - 2 * t) * 64;
#pragma unroll
            for (int nt = 0; nt < 4; ++nt) {
                const int rel_k = kbase + nt * 16 + l16;
#pragma unroll
                for (int j = 0; j < 4; ++j)
                    if (rel_k > wave * 16 + quad * 4 + j) sc[nt][j] = -3.0e38f;
            }
        }
        // online softmax (rows = quad*4+j; reduce across 16 lanes)
        float al[4];
#pragma unroll
        for (int j = 0; j < 4; ++j) {
            float mx = fmaxf(fmaxf(sc[0][j], sc[1][j]), fmaxf(sc[2][j], sc[3][j]));
#pragma unroll
            for (int off = 1; off <= 8; off <<= 1) mx = fmaxf(mx, __shfl_xor(mx, off));
            const float mn = fmaxf(m[j], mx);
            al[j] = __expf(m[j] - mn);
            m[j] = mn;
            float rs = 0.f;
#pragma unroll
            for (int nt = 0; nt < 4; ++nt) {
                sc[nt][j] = __expf(sc[nt][j] - mn);
                rs += sc[nt][j];
            }
#pragma unroll
            for (int off = 1; off <= 8; off <<= 1) rs += __shfl_xor(rs, off);
            l[j] = l[j] * al[j] + rs;
        }
        // P: C-layout -> LDS -> A-layout (wave-private rows)
#pragma unroll
        for (int nt = 0; nt < 4; ++nt)
#pragma unroll
            for (int j = 0; j < 4; ++j)
                Ps[wave * 16 + quad * 4 + j][nt * 16 + l16] = f2b(sc[nt][j]);
        asm volatile("s_waitcnt lgkmcnt(0)" ::: "memory");
        const bf16x8 aP0 = *(const bf16x8*)&Ps[wave * 16 + l16][quad * 8];
        const bf16x8 aP1 = *(const bf16x8*)&Ps[wave * 16 + l16][32 + quad * 8];
        // O = O*alpha + P V
#pragma unroll
        for (int nt = 0; nt < 4; ++nt)
#pragma unroll
            for (int j = 0; j < 4; ++j) O[nt][j] *= al[j];
#pragma unroll
        for (int nt = 0; nt < 4; ++nt) {
            const bf16x8 bV0 = *(const bf16x8*)&Vt[cur][nt * 16 + l16][quad * 8];
            const bf16x8 bV1 = *(const bf16x8*)&Vt[cur][nt * 16 + l16][32 + quad * 8];
            O[nt] = __builtin_amdgcn_mfma_f32_16x16x32_bf16(aP0, bV0, O[nt], 0, 0, 0);
            O[nt] = __builtin_amdgcn_mfma_f32_16x16x32_bf16(aP1, bV1, O[nt], 0, 0, 0);
        }
        // commit prefetched V into buf[nxt]
        if (c < nch - 1) {
#pragma unroll
            for (int i = 0; i < 8; ++i) Vt[nxt][wave * 8 + i][lane] = u.hh[i];
        }
    }

    // finalize: ctx compact [token][h*64+d], stride D
    const size_t hoC = (size_t)b * S * D + h * HD;
    float rl[4];
#pragma unroll
    for (int j = 0; j < 4; ++j) rl[j] = 1.0f / l[j];
#pragma unroll
    for (int nt = 0; nt < 4; ++nt)
#pragma unroll
        for (int j = 0; j < 4; ++j)
            ctx[hoC + (size_t)(q0 + wave * 16 + quad * 4 + j) * D + nt * 16 + l16] =
                f2b(O[nt][j] * rl[j]);
}

// ---------------- launcher ----------------
extern "C" void kernel_launch(void* const* d_in, const int* in_sizes, int n_in,
                              void* d_out, int out_size, void* d_ws, size_t ws_size,
                              hipStream_t stream) {
    const float* x     = (const float*)d_in[0];
    const float* ln1_g = (const float*)d_in[1];
    const float* ln1_b = (const float*)d_in[2];
    const float* Wq    = (const float*)d_in[3];
    const float* Wk    = (const float*)d_in[4];
    const float* Wv    = (const float*)d_in[5];
    const float* Wo    = (const float*)d_in[6];
    const float* bo    = (const float*)d_in[7];
    const float* ln2_g = (const float*)d_in[8];
    const float* ln2_b = (const float*)d_in[9];
    const float* W1    = (const float*)d_in[10];
    const float* b1    = (const float*)d_in[11];
    const float* W2    = (const float*)d_in[12];
    const float* b2    = (const float*)d_in[13];
    float* out = (float*)d_out;

    // workspace (MB), lifetime-overlapped; peak 64 MB:
    //   [ 0, 8): h (LN1 out)            -> W1T (conv after QKV gemm)
    //   [ 8,32): QKVb (packed, 24 MB)   \
    //   [32,40): ctx (attn out)          } -> hff [8,40) (32 MB)
    //   [40,48): h2 (LN2 out)
    //   [48,54): WqkvT   [54,56): WoT   [56,64): W2T
    //   x2 (fp32 residual) lives in d_out; final GEMM reads it in-place.
    char* ws = (char*)d_ws;
    const size_t MB = (size_t)1 << 20;
    bf16* h     = (bf16*)(ws + 0 * MB);
    bf16* W1T   = (bf16*)(ws + 0 * MB);
    bf16* QKVb  = (bf16*)(ws + 8 * MB);
    bf16* hff   = (bf16*)(ws + 8 * MB);
    bf16* ctx   = (bf16*)(ws + 32 * MB);
    bf16* h2    = (bf16*)(ws + 40 * MB);
    bf16* WqkvT = (bf16*)(ws + 48 * MB);
    bf16* WoT   = (bf16*)(ws + 54 * MB);
    bf16* W2T   = (bf16*)(ws + 56 * MB);

    // --- 0) transpose-convert weights (Wq/Wk/Wv fused into one B^T) ---
    dim3 gt(16, 16);
    convT_kernel<<<gt, 256, 0, stream>>>(Wq, WqkvT,                 D, D);
    convT_kernel<<<gt, 256, 0, stream>>>(Wk, WqkvT + (size_t)D * D, D, D);
    convT_kernel<<<gt, 256, 0, stream>>>(Wv, WqkvT + (size_t)2 * D * D, D, D);
    convT_kernel<<<gt, 256, 0, stream>>>(Wo, WoT, D, D);
    convT_kernel<<<dim3(64, 16), 256, 0, stream>>>(W2, W2T, DFF, D);
    // --- 1) LN1 ---
    ln_kernel<<<NR, 256, 0, stream>>>(x, ln1_g, ln1_b, h);
    // --- 2) QKV = h @ [Wq|Wk|Wv]   [4096,1024]x[1024,3072], 384 big blocks ---
    gemm256<0><<<(NR / 256) * (DQ / 128), 512, 0, stream>>>(
        h, WqkvT, nullptr, QKVb, NR, DQ, D);
    // h dead now -> W1T into [0,8)
    convT_kernel<<<dim3(16, 64), 256, 0, stream>>>(W1, W1T, D, DFF);
    // --- 3) flash attention -> ctx (512 blocks, 2/CU) ---
    fattn_kernel<<<dim3((S / 128) * B * H), 512, 0, stream>>>(QKVb, ctx);
    // --- 4) x2 = x + ctx @ Wo + bo   (fp32 into d_out), 512 blocks ---
    gemm_bt<1, 64, 1><<<(NR / 128) * (D / 64), 256, 0, stream>>>(
        ctx, WoT, bo, x, out, NR, D, D);
    // --- 5) LN2 ---
    ln_kernel<<<NR, 256, 0, stream>>>(out, ln2_g, ln2_b, h2);
    // --- 6) hff = gelu(h2 @ W1 + b1), 512 big blocks (2/CU, one generation) ---
    gemm256<2><<<(NR / 256) * (DFF / 128), 512, 0, stream>>>(
        h2, W1T, b1, hff, NR, DFF, D);
    // --- 7) out = x2 + hff @ W2 + b2   [4096,4096]x[4096,1024], in-place ---
    gemm_bt<1, 64, 1><<<(NR / 128) * (D / 64), 256, 0, stream>>>(
        hff, W2T, b2, out, out, NR, D, DFF);
}